// Round 1
// baseline (1977.079 us; speedup 1.0000x reference)
//
#include <hip/hip_runtime.h>

#define NNODES 50000
#define NEDGES 800000
#define HH 4
#define DD 64
#define FEAT 256   // HH*DD

// ---------- helpers ----------
__device__ __forceinline__ unsigned encf(float f) {
  unsigned u = __float_as_uint(f);
  return (u & 0x80000000u) ? ~u : (u | 0x80000000u);
}
__device__ __forceinline__ float decf(unsigned e) {
  unsigned u = (e & 0x80000000u) ? (e & 0x7fffffffu) : ~e;
  return __uint_as_float(u);
}

// ---------- fp32 tiled GEMM: C[M,Ncol] = A[M,K] @ B[K,Ncol] ----------
// 64x64 tile, BK=16, 256 threads, 4x4 per thread.
__global__ __launch_bounds__(256) void gemm_kernel(
    const float* __restrict__ A, const float* __restrict__ B,
    float* __restrict__ C, int M, int K, int Ncol) {
  __shared__ float As[16][68];  // [k][m], +4 pad keeps 16B alignment, breaks 16-way conflicts
  __shared__ float Bs[16][68];  // [k][n]
  const int tx = threadIdx.x & 15;
  const int ty = threadIdx.x >> 4;
  const int blockRow = blockIdx.x * 64;
  const int blockCol = blockIdx.y * 64;

  float acc[4][4] = {};

  for (int k0 = 0; k0 < K; k0 += 16) {
    // A tile: 64 rows x 16 k. thread loads rows r*16+ty, k=tx
#pragma unroll
    for (int r = 0; r < 4; ++r) {
      int row = blockRow + r * 16 + ty;
      float v = (row < M) ? A[(long)row * K + k0 + tx] : 0.f;
      As[tx][r * 16 + ty] = v;
    }
    // B tile: 16 k x 64 cols, float4 per thread
    {
      const float4 b4 = *(const float4*)(B + (long)(k0 + ty) * Ncol + blockCol + tx * 4);
      float4* bp = (float4*)&Bs[ty][tx * 4];
      *bp = b4;
    }
    __syncthreads();
#pragma unroll
    for (int k = 0; k < 16; ++k) {
      float4 a4 = *(const float4*)&As[k][ty * 4];
      float4 b4 = *(const float4*)&Bs[k][tx * 4];
      float a[4] = {a4.x, a4.y, a4.z, a4.w};
      float b[4] = {b4.x, b4.y, b4.z, b4.w};
#pragma unroll
      for (int i = 0; i < 4; ++i)
#pragma unroll
        for (int j = 0; j < 4; ++j) acc[i][j] += a[i] * b[j];
    }
    __syncthreads();
  }

#pragma unroll
  for (int i = 0; i < 4; ++i) {
    int row = blockRow + ty * 4 + i;
    if (row < M) {
      float4 o = make_float4(acc[i][0], acc[i][1], acc[i][2], acc[i][3]);
      *(float4*)(C + (long)row * Ncol + blockCol + tx * 4) = o;
    }
  }
}

// ---------- per-(node,head) attention dots: el/er ----------
__global__ __launch_bounds__(256) void eler_kernel(
    const float* __restrict__ feat, const float* __restrict__ al,
    const float* __restrict__ ar, float* __restrict__ el, float* __restrict__ er) {
  int n = blockIdx.x;
  int t = threadIdx.x;       // 0..255
  int h = t >> 6, d = t & 63;
  float v = feat[n * FEAT + t];
  float pl = v * al[h * DD + d];
  float pr = v * ar[h * DD + d];
#pragma unroll
  for (int off = 32; off; off >>= 1) {
    pl += __shfl_down(pl, off);
    pr += __shfl_down(pr, off);
  }
  if (d == 0) {
    el[n * HH + h] = pl;
    er[n * HH + h] = pr;
  }
}

// ---------- edge scores + segment max ----------
__global__ __launch_bounds__(256) void edge_max_kernel(
    const int* __restrict__ src, const int* __restrict__ dst,
    const float* __restrict__ el, const float* __restrict__ er,
    float* __restrict__ ebuf, unsigned* __restrict__ menc) {
  int idx = blockIdx.x * 256 + threadIdx.x;
  if (idx >= NEDGES * HH) return;
  int eid = idx >> 2, h = idx & 3;
  int s = src[eid], d = dst[eid];
  float e = el[s * HH + h] + er[d * HH + h];
  e = e > 0.f ? e : 0.2f * e;
  ebuf[idx] = e;
  atomicMax(&menc[d * HH + h], encf(e));
}

// ---------- exp(e - m) + segment sum ----------
__global__ __launch_bounds__(256) void edge_exp_kernel(
    const int* __restrict__ dst, const float* __restrict__ ebuf,
    const unsigned* __restrict__ menc, float* __restrict__ abuf,
    float* __restrict__ ssum) {
  int idx = blockIdx.x * 256 + threadIdx.x;
  if (idx >= NEDGES * HH) return;
  int eid = idx >> 2, h = idx & 3;
  int d = dst[eid];
  float m = decf(menc[d * HH + h]);
  float a = expf(ebuf[idx] - m);
  abuf[idx] = a;
  atomicAdd(&ssum[d * HH + h], a);
}

// ---------- weighted gather-scatter aggregation ----------
__global__ __launch_bounds__(256) void aggregate_kernel(
    const int* __restrict__ src, const int* __restrict__ dst,
    const float* __restrict__ abuf, const float* __restrict__ feat,
    float* __restrict__ agg) {
  int eid = blockIdx.x;
  int t = threadIdx.x;
  int h = t >> 6;
  int s = src[eid], d = dst[eid];
  float a = abuf[eid * HH + h];
  float v = a * feat[s * FEAT + t];
  atomicAdd(&agg[d * FEAT + t], v);
}

// ---------- layer-1 epilogue: divide by s, ELU, in place ----------
__global__ __launch_bounds__(256) void finalize1_kernel(
    float* __restrict__ agg, const float* __restrict__ ssum) {
  int idx = blockIdx.x * 256 + threadIdx.x;
  if (idx >= NNODES * FEAT) return;
  int n = idx >> 8;
  int h = (idx >> 6) & 3;
  float sv = ssum[n * HH + h];
  sv = sv > 0.f ? sv : 1.f;
  float v = agg[idx] / sv;
  v = v > 0.f ? v : (expf(v) - 1.f);
  agg[idx] = v;
}

// ---------- layer-2 epilogue: divide by s, mean over heads ----------
__global__ __launch_bounds__(256) void finalize2_kernel(
    const float* __restrict__ agg, const float* __restrict__ ssum,
    float* __restrict__ out) {
  int idx = blockIdx.x * 256 + threadIdx.x;
  if (idx >= NNODES * DD) return;
  int n = idx >> 6, d = idx & 63;
  float acc = 0.f;
#pragma unroll
  for (int h = 0; h < HH; ++h) {
    float sv = ssum[n * HH + h];
    sv = sv > 0.f ? sv : 1.f;
    acc += agg[n * FEAT + h * DD + d] / sv;
  }
  out[idx] = 0.25f * acc;
}

extern "C" void kernel_launch(void* const* d_in, const int* in_sizes, int n_in,
                              void* d_out, int out_size, void* d_ws, size_t ws_size,
                              hipStream_t stream) {
  const float* x   = (const float*)d_in[0];
  const int*   src = (const int*)d_in[1];
  const int*   dst = (const int*)d_in[2];
  const float* W1  = (const float*)d_in[3];
  const float* al1 = (const float*)d_in[4];
  const float* ar1 = (const float*)d_in[5];
  const float* W2  = (const float*)d_in[6];
  const float* al2 = (const float*)d_in[7];
  const float* ar2 = (const float*)d_in[8];
  float* out = (float*)d_out;

  // workspace layout (floats)
  float* ws = (float*)d_ws;
  float*    bufA = ws;                       // 12.8M : feat1 / feat2
  float*    bufB = bufA + NNODES * FEAT;     // 12.8M : agg1 -> h -> agg2
  float*    ebuf = bufB + NNODES * FEAT;     // 3.2M
  float*    abuf = ebuf + NEDGES * HH;       // 3.2M
  float*    el   = abuf + NEDGES * HH;       // 200K
  float*    er   = el + NNODES * HH;         // 200K
  unsigned* menc = (unsigned*)(er + NNODES * HH);  // 200K
  float*    ssum = (float*)(menc + NNODES * HH);   // 200K

  const int gemmRows = (NNODES + 63) / 64;
  dim3 gemmGrid(gemmRows, FEAT / 64);
  const int edgeBlocks = (NEDGES * HH + 255) / 256;

  // ================= layer 1 =================
  gemm_kernel<<<gemmGrid, 256, 0, stream>>>(x, W1, bufA, NNODES, 512, FEAT);
  eler_kernel<<<NNODES, 256, 0, stream>>>(bufA, al1, ar1, el, er);
  hipMemsetAsync(menc, 0, 2 * NNODES * HH * sizeof(float), stream);  // menc + ssum
  edge_max_kernel<<<edgeBlocks, 256, 0, stream>>>(src, dst, el, er, ebuf, menc);
  edge_exp_kernel<<<edgeBlocks, 256, 0, stream>>>(dst, ebuf, menc, abuf, ssum);
  hipMemsetAsync(bufB, 0, (size_t)NNODES * FEAT * sizeof(float), stream);
  aggregate_kernel<<<NEDGES, 256, 0, stream>>>(src, dst, abuf, bufA, bufB);
  finalize1_kernel<<<(NNODES * FEAT + 255) / 256, 256, 0, stream>>>(bufB, ssum);

  // ================= layer 2 =================
  gemm_kernel<<<gemmGrid, 256, 0, stream>>>(bufB, W2, bufA, NNODES, 256, FEAT);
  eler_kernel<<<NNODES, 256, 0, stream>>>(bufA, al2, ar2, el, er);
  hipMemsetAsync(menc, 0, 2 * NNODES * HH * sizeof(float), stream);
  edge_max_kernel<<<edgeBlocks, 256, 0, stream>>>(src, dst, el, er, ebuf, menc);
  edge_exp_kernel<<<edgeBlocks, 256, 0, stream>>>(dst, ebuf, menc, abuf, ssum);
  hipMemsetAsync(bufB, 0, (size_t)NNODES * FEAT * sizeof(float), stream);
  aggregate_kernel<<<NEDGES, 256, 0, stream>>>(src, dst, abuf, bufA, bufB);
  finalize2_kernel<<<(NNODES * DD + 255) / 256, 256, 0, stream>>>(bufB, ssum, out);
}

// Round 2
// 1117.855 us; speedup vs baseline: 1.7686x; 1.7686x over previous
//
#include <hip/hip_runtime.h>

#define NNODES 50000
#define NEDGES 800000
#define HH 4
#define DD 64
#define FEAT 256   // HH*DD
#define NB ((NNODES + 255) / 256)   // 196 scan blocks

// ---------- fp32 tiled GEMM: C[M,Ncol] = A[M,K] @ B[K,Ncol] ----------
__global__ __launch_bounds__(256) void gemm_kernel(
    const float* __restrict__ A, const float* __restrict__ B,
    float* __restrict__ C, int M, int K, int Ncol) {
  __shared__ float As[16][68];
  __shared__ float Bs[16][68];
  const int tx = threadIdx.x & 15;
  const int ty = threadIdx.x >> 4;
  const int blockRow = blockIdx.x * 64;
  const int blockCol = blockIdx.y * 64;

  float acc[4][4] = {};

  for (int k0 = 0; k0 < K; k0 += 16) {
#pragma unroll
    for (int r = 0; r < 4; ++r) {
      int row = blockRow + r * 16 + ty;
      float v = (row < M) ? A[(long)row * K + k0 + tx] : 0.f;
      As[tx][r * 16 + ty] = v;
    }
    {
      const float4 b4 = *(const float4*)(B + (long)(k0 + ty) * Ncol + blockCol + tx * 4);
      float4* bp = (float4*)&Bs[ty][tx * 4];
      *bp = b4;
    }
    __syncthreads();
#pragma unroll
    for (int k = 0; k < 16; ++k) {
      float4 a4 = *(const float4*)&As[k][ty * 4];
      float4 b4 = *(const float4*)&Bs[k][tx * 4];
      float a[4] = {a4.x, a4.y, a4.z, a4.w};
      float b[4] = {b4.x, b4.y, b4.z, b4.w};
#pragma unroll
      for (int i = 0; i < 4; ++i)
#pragma unroll
        for (int j = 0; j < 4; ++j) acc[i][j] += a[i] * b[j];
    }
    __syncthreads();
  }

#pragma unroll
  for (int i = 0; i < 4; ++i) {
    int row = blockRow + ty * 4 + i;
    if (row < M) {
      float4 o = make_float4(acc[i][0], acc[i][1], acc[i][2], acc[i][3]);
      *(float4*)(C + (long)row * Ncol + blockCol + tx * 4) = o;
    }
  }
}

// ---------- per-(node,head) attention dots: el/er ----------
__global__ __launch_bounds__(256) void eler_kernel(
    const float* __restrict__ feat, const float* __restrict__ al,
    const float* __restrict__ ar, float* __restrict__ el, float* __restrict__ er) {
  int n = blockIdx.x;
  int t = threadIdx.x;
  int h = t >> 6, d = t & 63;
  float v = feat[n * FEAT + t];
  float pl = v * al[h * DD + d];
  float pr = v * ar[h * DD + d];
#pragma unroll
  for (int off = 32; off; off >>= 1) {
    pl += __shfl_down(pl, off);
    pr += __shfl_down(pr, off);
  }
  if (d == 0) {
    el[n * HH + h] = pl;
    er[n * HH + h] = pr;
  }
}

// ---------- CSR build: histogram ----------
__global__ __launch_bounds__(256) void hist_kernel(const int* __restrict__ dst,
                                                   int* __restrict__ deg) {
  int e = blockIdx.x * 256 + threadIdx.x;
  if (e < NEDGES) atomicAdd(&deg[dst[e]], 1);
}

// ---------- CSR build: 3-step exclusive scan over deg -> off[NNODES+1] ----------
__global__ __launch_bounds__(256) void scan_block_kernel(const int* __restrict__ deg,
                                                         int* __restrict__ off,
                                                         int* __restrict__ bsum) {
  __shared__ int tmp[256];
  int b = blockIdx.x, t = threadIdx.x;
  int i = b * 256 + t;
  int v = (i < NNODES) ? deg[i] : 0;
  tmp[t] = v;
  __syncthreads();
  for (int s = 1; s < 256; s <<= 1) {
    int add = (t >= s) ? tmp[t - s] : 0;
    __syncthreads();
    tmp[t] += add;
    __syncthreads();
  }
  if (i < NNODES) off[i + 1] = tmp[t];  // inclusive within block
  if (t == 255) bsum[b] = tmp[255];
}

__global__ __launch_bounds__(256) void scan_top_kernel(int* __restrict__ bsum) {
  __shared__ int tmp[256];
  int t = threadIdx.x;
  int v = (t < NB) ? bsum[t] : 0;
  tmp[t] = v;
  __syncthreads();
  for (int s = 1; s < 256; s <<= 1) {
    int add = (t >= s) ? tmp[t - s] : 0;
    __syncthreads();
    tmp[t] += add;
    __syncthreads();
  }
  if (t < NB) bsum[t] = tmp[t] - v;  // exclusive block offsets
}

__global__ __launch_bounds__(256) void scan_add_kernel(int* __restrict__ off,
                                                       const int* __restrict__ bsum) {
  int b = blockIdx.x, t = threadIdx.x;
  int i = b * 256 + t;
  if (i < NNODES) off[i + 1] += bsum[b];
  if (i == 0) off[0] = 0;
}

__global__ __launch_bounds__(256) void cursor_kernel(const int* __restrict__ off,
                                                     int* __restrict__ cursor) {
  int i = blockIdx.x * 256 + threadIdx.x;
  if (i < NNODES) cursor[i] = off[i];
}

// ---------- CSR build: scatter src by dst-group ----------
__global__ __launch_bounds__(256) void scatter_kernel(const int* __restrict__ src,
                                                      const int* __restrict__ dst,
                                                      int* __restrict__ cursor,
                                                      int* __restrict__ csr_src) {
  int e = blockIdx.x * 256 + threadIdx.x;
  if (e >= NEDGES) return;
  int d = dst[e];
  int pos = atomicAdd(&cursor[d], 1);
  csr_src[pos] = src[e];
}

// ---------- fused per-dst-node GAT: scores + softmax + weighted aggregate ----------
// Block per node, 256 threads; thread t owns (h=t>>6, d=t&63).
template <int LAYER>
__global__ __launch_bounds__(256) void gat_agg_kernel(
    const int* __restrict__ off, const int* __restrict__ csr_src,
    const float* __restrict__ el, const float* __restrict__ er,
    const float* __restrict__ feat, float* __restrict__ outp) {
  __shared__ float sh[256];
  int n = blockIdx.x;
  int t = threadIdx.x;
  int h = t >> 6;
  int beg = off[n], end = off[n + 1];
  float acc = 0.f, ssum = 0.f;
  if (beg < end) {
    float erd = er[n * HH + h];
    float m = -INFINITY;
    for (int i = beg; i < end; ++i) {
      int s = csr_src[i];                 // broadcast load
      float e = el[s * HH + h] + erd;     // broadcast within wave
      e = e > 0.f ? e : 0.2f * e;
      m = fmaxf(m, e);
    }
    for (int i = beg; i < end; ++i) {
      int s = csr_src[i];
      float e = el[s * HH + h] + erd;
      e = e > 0.f ? e : 0.2f * e;
      float a = expf(e - m);
      ssum += a;
      acc = fmaf(a, feat[s * FEAT + t], acc);  // coalesced 1KB gather
    }
  }
  float v = (ssum > 0.f) ? acc / ssum : 0.f;
  if (LAYER == 1) {
    v = v > 0.f ? v : (expf(v) - 1.f);  // ELU
    outp[n * FEAT + t] = v;
  } else {
    sh[t] = v;
    __syncthreads();
    if (t < DD) {
      float o = 0.25f * (sh[t] + sh[t + 64] + sh[t + 128] + sh[t + 192]);
      outp[n * DD + t] = o;
    }
  }
}

extern "C" void kernel_launch(void* const* d_in, const int* in_sizes, int n_in,
                              void* d_out, int out_size, void* d_ws, size_t ws_size,
                              hipStream_t stream) {
  const float* x   = (const float*)d_in[0];
  const int*   src = (const int*)d_in[1];
  const int*   dst = (const int*)d_in[2];
  const float* W1  = (const float*)d_in[3];
  const float* al1 = (const float*)d_in[4];
  const float* ar1 = (const float*)d_in[5];
  const float* W2  = (const float*)d_in[6];
  const float* al2 = (const float*)d_in[7];
  const float* ar2 = (const float*)d_in[8];
  float* out = (float*)d_out;

  // workspace layout
  float* ws = (float*)d_ws;
  float* bufA = ws;                        // NNODES*FEAT : feat
  float* bufB = bufA + NNODES * FEAT;      // NNODES*FEAT : h (layer-1 out)
  float* el   = bufB + NNODES * FEAT;      // NNODES*HH
  float* er   = el + NNODES * HH;          // NNODES*HH
  int* deg     = (int*)(er + NNODES * HH); // NNODES
  int* off     = deg + NNODES;             // NNODES+1
  int* cursor  = off + NNODES + 1;         // NNODES
  int* bsum    = cursor + NNODES;          // 256
  int* csr_src = bsum + 256;               // NEDGES

  const int gemmRows = (NNODES + 63) / 64;
  dim3 gemmGrid(gemmRows, FEAT / 64);
  const int edgeBlocks = (NEDGES + 255) / 256;

  // ---------- CSR build (shared by both layers) ----------
  hipMemsetAsync(deg, 0, NNODES * sizeof(int), stream);
  hist_kernel<<<edgeBlocks, 256, 0, stream>>>(dst, deg);
  scan_block_kernel<<<NB, 256, 0, stream>>>(deg, off, bsum);
  scan_top_kernel<<<1, 256, 0, stream>>>(bsum);
  scan_add_kernel<<<NB, 256, 0, stream>>>(off, bsum);
  cursor_kernel<<<NB, 256, 0, stream>>>(off, cursor);
  scatter_kernel<<<edgeBlocks, 256, 0, stream>>>(src, dst, cursor, csr_src);

  // ---------- layer 1 ----------
  gemm_kernel<<<gemmGrid, 256, 0, stream>>>(x, W1, bufA, NNODES, 512, FEAT);
  eler_kernel<<<NNODES, 256, 0, stream>>>(bufA, al1, ar1, el, er);
  gat_agg_kernel<1><<<NNODES, 256, 0, stream>>>(off, csr_src, el, er, bufA, bufB);

  // ---------- layer 2 ----------
  gemm_kernel<<<gemmGrid, 256, 0, stream>>>(bufB, W2, bufA, NNODES, 256, FEAT);
  eler_kernel<<<NNODES, 256, 0, stream>>>(bufA, al2, ar2, el, er);
  gat_agg_kernel<2><<<NNODES, 256, 0, stream>>>(off, csr_src, el, er, bufA, out);
}

// Round 3
// 861.145 us; speedup vs baseline: 2.2959x; 1.2981x over previous
//
#include <hip/hip_runtime.h>

#define NNODES 50000
#define NEDGES 800000
#define HH 4
#define DD 64
#define FEAT 256   // HH*DD
#define NB ((NNODES + 255) / 256)
#define ECAP 512   // LDS edge cap per node (deg>ECAP falls back; Poisson(16) => never)

// ---------- fp32 tiled GEMM: C[M,Ncol] = A[M,K] @ B[K,Ncol] ----------
__global__ __launch_bounds__(256) void gemm_kernel(
    const float* __restrict__ A, const float* __restrict__ B,
    float* __restrict__ C, int M, int K, int Ncol) {
  __shared__ float As[16][68];
  __shared__ float Bs[16][68];
  const int tx = threadIdx.x & 15;
  const int ty = threadIdx.x >> 4;
  const int blockRow = blockIdx.x * 64;
  const int blockCol = blockIdx.y * 64;

  float acc[4][4] = {};

  for (int k0 = 0; k0 < K; k0 += 16) {
#pragma unroll
    for (int r = 0; r < 4; ++r) {
      int row = blockRow + r * 16 + ty;
      float v = (row < M) ? A[(long)row * K + k0 + tx] : 0.f;
      As[tx][r * 16 + ty] = v;
    }
    {
      const float4 b4 = *(const float4*)(B + (long)(k0 + ty) * Ncol + blockCol + tx * 4);
      float4* bp = (float4*)&Bs[ty][tx * 4];
      *bp = b4;
    }
    __syncthreads();
#pragma unroll
    for (int k = 0; k < 16; ++k) {
      float4 a4 = *(const float4*)&As[k][ty * 4];
      float4 b4 = *(const float4*)&Bs[k][tx * 4];
      float a[4] = {a4.x, a4.y, a4.z, a4.w};
      float b[4] = {b4.x, b4.y, b4.z, b4.w};
#pragma unroll
      for (int i = 0; i < 4; ++i)
#pragma unroll
        for (int j = 0; j < 4; ++j) acc[i][j] += a[i] * b[j];
    }
    __syncthreads();
  }

#pragma unroll
  for (int i = 0; i < 4; ++i) {
    int row = blockRow + ty * 4 + i;
    if (row < M) {
      float4 o = make_float4(acc[i][0], acc[i][1], acc[i][2], acc[i][3]);
      *(float4*)(C + (long)row * Ncol + blockCol + tx * 4) = o;
    }
  }
}

// ---------- per-(node,head) attention dots: el/er ----------
__global__ __launch_bounds__(256) void eler_kernel(
    const float* __restrict__ feat, const float* __restrict__ al,
    const float* __restrict__ ar, float* __restrict__ el, float* __restrict__ er) {
  int n = blockIdx.x;
  int t = threadIdx.x;
  int h = t >> 6, d = t & 63;
  float v = feat[n * FEAT + t];
  float pl = v * al[h * DD + d];
  float pr = v * ar[h * DD + d];
#pragma unroll
  for (int off = 32; off; off >>= 1) {
    pl += __shfl_down(pl, off);
    pr += __shfl_down(pr, off);
  }
  if (d == 0) {
    el[n * HH + h] = pl;
    er[n * HH + h] = pr;
  }
}

// ---------- CSR build ----------
__global__ __launch_bounds__(256) void hist_kernel(const int* __restrict__ dst,
                                                   int* __restrict__ deg) {
  int e = blockIdx.x * 256 + threadIdx.x;
  if (e < NEDGES) atomicAdd(&deg[dst[e]], 1);
}

__global__ __launch_bounds__(256) void scan_block_kernel(const int* __restrict__ deg,
                                                         int* __restrict__ off,
                                                         int* __restrict__ bsum) {
  __shared__ int tmp[256];
  int b = blockIdx.x, t = threadIdx.x;
  int i = b * 256 + t;
  int v = (i < NNODES) ? deg[i] : 0;
  tmp[t] = v;
  __syncthreads();
  for (int s = 1; s < 256; s <<= 1) {
    int add = (t >= s) ? tmp[t - s] : 0;
    __syncthreads();
    tmp[t] += add;
    __syncthreads();
  }
  if (i < NNODES) off[i + 1] = tmp[t];
  if (t == 255) bsum[b] = tmp[255];
}

__global__ __launch_bounds__(256) void scan_top_kernel(int* __restrict__ bsum) {
  __shared__ int tmp[256];
  int t = threadIdx.x;
  int v = (t < NB) ? bsum[t] : 0;
  tmp[t] = v;
  __syncthreads();
  for (int s = 1; s < 256; s <<= 1) {
    int add = (t >= s) ? tmp[t - s] : 0;
    __syncthreads();
    tmp[t] += add;
    __syncthreads();
  }
  if (t < NB) bsum[t] = tmp[t] - v;
}

__global__ __launch_bounds__(256) void scan_add_kernel(int* __restrict__ off,
                                                       const int* __restrict__ bsum) {
  int b = blockIdx.x, t = threadIdx.x;
  int i = b * 256 + t;
  if (i < NNODES) off[i + 1] += bsum[b];
  if (i == 0) off[0] = 0;
}

__global__ __launch_bounds__(256) void cursor_kernel(const int* __restrict__ off,
                                                     int* __restrict__ cursor) {
  int i = blockIdx.x * 256 + threadIdx.x;
  if (i < NNODES) cursor[i] = off[i];
}

__global__ __launch_bounds__(256) void scatter_kernel(const int* __restrict__ src,
                                                      const int* __restrict__ dst,
                                                      int* __restrict__ cursor,
                                                      int* __restrict__ csr_src) {
  int e = blockIdx.x * 256 + threadIdx.x;
  if (e >= NEDGES) return;
  int d = dst[e];
  int pos = atomicAdd(&cursor[d], 1);
  csr_src[pos] = src[e];
}

// ---------- fused per-dst-node GAT: scores + softmax + weighted aggregate ----------
// Block per node, 256 threads.
// Phase 1: thread t -> (edge j = t>>2 strided, head hh = t&3): score once, into LDS.
// Phase 2: thread t -> (h = t>>6, d = t&63): pure gather-fmaf with LDS weights.
template <int LAYER>
__global__ __launch_bounds__(256) void gat_agg_kernel(
    const int* __restrict__ off, const int* __restrict__ csr_src,
    const float* __restrict__ el, const float* __restrict__ er,
    const float* __restrict__ feat, float* __restrict__ outp) {
  __shared__ float sh_a[ECAP * HH];  // 8 KB
  __shared__ int sh_s[ECAP];         // 2 KB
  __shared__ float red[256];         // 1 KB
  const int n = blockIdx.x;
  const int t = threadIdx.x;
  const int h = t >> 6;
  const int beg = off[n];
  const int deg = off[n + 1] - beg;
  float v = 0.f;

  if (deg > 0 && deg <= ECAP) {
    // ---- phase 1: scores ----
    const int hh = t & 3, j0 = t >> 2;
    const float erd = er[n * HH + hh];
    float m = -INFINITY;
    for (int j = j0; j < deg; j += 64) {
      int s = csr_src[beg + j];
      if (hh == 0) sh_s[j] = s;
      float e = el[s * HH + hh] + erd;
      e = e > 0.f ? e : 0.2f * e;
      sh_a[j * HH + hh] = e;
      m = fmaxf(m, e);
    }
    red[t] = m;
    __syncthreads();
#pragma unroll
    for (int sft = 128; sft >= 4; sft >>= 1) {
      if (t < sft) red[t] = fmaxf(red[t], red[t + sft]);
      __syncthreads();
    }
    const float mh = red[hh];
    __syncthreads();  // all reads of red done before overwrite
    float ps = 0.f;
    for (int j = j0; j < deg; j += 64) {
      float a = __expf(sh_a[j * HH + hh] - mh);
      sh_a[j * HH + hh] = a;
      ps += a;
    }
    red[t] = ps;
    __syncthreads();
#pragma unroll
    for (int sft = 128; sft >= 4; sft >>= 1) {
      if (t < sft) red[t] += red[t + sft];
      __syncthreads();
    }
    const float sv = red[hh];
    const float sinv = sv > 0.f ? 1.f / sv : 0.f;
    for (int j = j0; j < deg; j += 64) sh_a[j * HH + hh] *= sinv;
    __syncthreads();

    // ---- phase 2: aggregate ----
    float acc = 0.f;
    int j = 0;
    for (; j + 4 <= deg; j += 4) {
      int s0 = sh_s[j], s1 = sh_s[j + 1], s2 = sh_s[j + 2], s3 = sh_s[j + 3];
      float a0 = sh_a[j * HH + h], a1 = sh_a[(j + 1) * HH + h];
      float a2 = sh_a[(j + 2) * HH + h], a3 = sh_a[(j + 3) * HH + h];
      float f0 = feat[(long)s0 * FEAT + t];
      float f1 = feat[(long)s1 * FEAT + t];
      float f2 = feat[(long)s2 * FEAT + t];
      float f3 = feat[(long)s3 * FEAT + t];
      acc = fmaf(a0, f0, acc);
      acc = fmaf(a1, f1, acc);
      acc = fmaf(a2, f2, acc);
      acc = fmaf(a3, f3, acc);
    }
    for (; j < deg; ++j) {
      acc = fmaf(sh_a[j * HH + h], feat[(long)sh_s[j] * FEAT + t], acc);
    }
    v = acc;
  } else if (deg > ECAP) {
    // fallback: recompute path (unreachable for Poisson(16), kept for safety)
    const float erd = er[n * HH + h];
    float m = -INFINITY;
    for (int i = beg; i < beg + deg; ++i) {
      int s = csr_src[i];
      float e = el[s * HH + h] + erd;
      e = e > 0.f ? e : 0.2f * e;
      m = fmaxf(m, e);
    }
    float acc = 0.f, ssum = 0.f;
    for (int i = beg; i < beg + deg; ++i) {
      int s = csr_src[i];
      float e = el[s * HH + h] + erd;
      e = e > 0.f ? e : 0.2f * e;
      float a = __expf(e - m);
      ssum += a;
      acc = fmaf(a, feat[(long)s * FEAT + t], acc);
    }
    v = (ssum > 0.f) ? acc / ssum : 0.f;
  }

  // ---- epilogue ----
  if (LAYER == 1) {
    v = v > 0.f ? v : (__expf(v) - 1.f);  // ELU
    outp[n * FEAT + t] = v;
  } else {
    __syncthreads();
    red[t] = v;
    __syncthreads();
    if (t < DD) {
      float o = 0.25f * (red[t] + red[t + 64] + red[t + 128] + red[t + 192]);
      outp[n * DD + t] = o;
    }
  }
}

extern "C" void kernel_launch(void* const* d_in, const int* in_sizes, int n_in,
                              void* d_out, int out_size, void* d_ws, size_t ws_size,
                              hipStream_t stream) {
  const float* x   = (const float*)d_in[0];
  const int*   src = (const int*)d_in[1];
  const int*   dst = (const int*)d_in[2];
  const float* W1  = (const float*)d_in[3];
  const float* al1 = (const float*)d_in[4];
  const float* ar1 = (const float*)d_in[5];
  const float* W2  = (const float*)d_in[6];
  const float* al2 = (const float*)d_in[7];
  const float* ar2 = (const float*)d_in[8];
  float* out = (float*)d_out;

  // workspace layout
  float* ws = (float*)d_ws;
  float* bufA = ws;                        // NNODES*FEAT : feat
  float* bufB = bufA + NNODES * FEAT;      // NNODES*FEAT : h (layer-1 out)
  float* el   = bufB + NNODES * FEAT;      // NNODES*HH
  float* er   = el + NNODES * HH;          // NNODES*HH
  int* deg     = (int*)(er + NNODES * HH); // NNODES
  int* off     = deg + NNODES;             // NNODES+1
  int* cursor  = off + NNODES + 1;         // NNODES
  int* bsum    = cursor + NNODES;          // 256
  int* csr_src = bsum + 256;               // NEDGES

  const int gemmRows = (NNODES + 63) / 64;
  dim3 gemmGrid(gemmRows, FEAT / 64);
  const int edgeBlocks = (NEDGES + 255) / 256;

  // ---------- CSR build (shared by both layers) ----------
  hipMemsetAsync(deg, 0, NNODES * sizeof(int), stream);
  hist_kernel<<<edgeBlocks, 256, 0, stream>>>(dst, deg);
  scan_block_kernel<<<NB, 256, 0, stream>>>(deg, off, bsum);
  scan_top_kernel<<<1, 256, 0, stream>>>(bsum);
  scan_add_kernel<<<NB, 256, 0, stream>>>(off, bsum);
  cursor_kernel<<<NB, 256, 0, stream>>>(off, cursor);
  scatter_kernel<<<edgeBlocks, 256, 0, stream>>>(src, dst, cursor, csr_src);

  // ---------- layer 1 ----------
  gemm_kernel<<<gemmGrid, 256, 0, stream>>>(x, W1, bufA, NNODES, 512, FEAT);
  eler_kernel<<<NNODES, 256, 0, stream>>>(bufA, al1, ar1, el, er);
  gat_agg_kernel<1><<<NNODES, 256, 0, stream>>>(off, csr_src, el, er, bufA, bufB);

  // ---------- layer 2 ----------
  gemm_kernel<<<gemmGrid, 256, 0, stream>>>(bufB, W2, bufA, NNODES, 256, FEAT);
  eler_kernel<<<NNODES, 256, 0, stream>>>(bufA, al2, ar2, el, er);
  gat_agg_kernel<2><<<NNODES, 256, 0, stream>>>(off, csr_src, el, er, bufA, out);
}

// Round 4
// 781.655 us; speedup vs baseline: 2.5293x; 1.1017x over previous
//
#include <hip/hip_runtime.h>

#define NNODES 50000
#define NEDGES 800000
#define HH 4
#define DD 64
#define FEAT 256   // HH*DD
#define NB ((NNODES + 255) / 256)
#define ECAP 512
#define MPAD 50048  // 391 * 128

typedef __attribute__((ext_vector_type(8))) short frag_ab;   // 8 bf16
typedef __attribute__((ext_vector_type(4))) float frag_cd;   // 4 fp32

// ---------- bf16 helpers (RNE) ----------
__device__ __forceinline__ short f2bf(float v) {
  union { float f; unsigned u; } x; x.f = v;
  unsigned r = x.u + 0x7fffu + ((x.u >> 16) & 1u);
  return (short)(r >> 16);
}
__device__ __forceinline__ float bf2f(short b) {
  union { float f; unsigned u; } x;
  x.u = ((unsigned)(unsigned short)b) << 16;
  return x.f;
}

// ---------- split A (fp32 MxK) -> A' bf16 [MPAD x 2K] = [Ahi | Alo] ----------
__global__ __launch_bounds__(256) void split_a_kernel(
    const float* __restrict__ A, short* __restrict__ Ap, int M, int K) {
  int k = blockIdx.x * 256 + threadIdx.x;
  int m = blockIdx.y;
  float v = (m < M) ? A[(size_t)m * K + k] : 0.f;
  short hi = f2bf(v);
  float lo = v - bf2f(hi);
  size_t base = (size_t)m * 2 * K;
  Ap[base + k] = hi;
  Ap[base + K + k] = f2bf(lo);
}

// ---------- prep B (fp32 KxN, N=256) -> B'^T bf16 [N x 2K] = [Bhi | Blo] ----------
__global__ __launch_bounds__(256) void prep_b_kernel(
    const float* __restrict__ B, short* __restrict__ Bp, int K) {
  int idx = blockIdx.x * 256 + threadIdx.x;
  if (idx >= K * 256) return;
  int k = idx >> 8, n = idx & 255;
  float v = B[idx];
  short hi = f2bf(v);
  float lo = v - bf2f(hi);
  Bp[(size_t)n * 2 * K + k] = hi;
  Bp[(size_t)n * 2 * K + K + k] = f2bf(lo);
}

// ---------- MFMA GEMM: C[M,256] = split3(A) @ split3(B) ----------
// A': [MPAD x 2K] bf16 row-major; B': [256 x 2K] bf16 row-major (B^T layout).
// 128x128 tile, BK=32, 4 waves (2x2 of 64x64), 16x16x32 bf16 MFMA.
__global__ __launch_bounds__(256) void mfma_gemm_kernel(
    const short* __restrict__ Ap, const short* __restrict__ Bp,
    float* __restrict__ C, int M, int K) {
  __shared__ short As[128 * 32];  // 8 KB, row-major [row][32]
  __shared__ short Bs[128 * 32];  // 8 KB, row-major [n][32]
  const int tid = threadIdx.x;
  const int w = tid >> 6, lane = tid & 63;
  const int q = lane >> 4, ln = lane & 15;
  const int rowBase = blockIdx.x * 128;
  const int colBase = blockIdx.y * 128;
  const int K2 = 2 * K;
  const int wm = (w >> 1) * 64;  // wave tile origin in M
  const int wn = (w & 1) * 64;   // wave tile origin in N

  frag_cd acc[4][4] = {};

  const int i1 = K >> 5;  // iters per segment
  // staging thread roles
  const int srow = lane >> 2;           // 0..15 within 16-row group
  const int schunk = (lane & 3) * 8;    // half offset within 64B row

  for (int it = 0; it < 3 * i1; ++it) {
    int s = (it >= i1) + (it >= 2 * i1);
    int ib = it - (s == 1 ? i1 : (s == 2 ? 2 * i1 : 0));
    int kA = (s == 1 ? K : 0) + ib * 32;
    int kB = (s == 2 ? K : 0) + ib * 32;

    __syncthreads();  // previous compute done before overwrite
    // stage A: wave w covers rows [w*32, w*32+32)
#pragma unroll
    for (int j = 0; j < 2; ++j) {
      int rloc = w * 32 + j * 16 + srow;
      const short* g = Ap + (size_t)(rowBase + rloc) * K2 + kA + schunk;
      __builtin_amdgcn_global_load_lds(
          (const __attribute__((address_space(1))) void*)g,
          (__attribute__((address_space(3))) void*)(&As[(w * 32 + j * 16) * 32 + lane * 8]),
          16, 0, 0);
    }
    // stage B
#pragma unroll
    for (int j = 0; j < 2; ++j) {
      int rloc = w * 32 + j * 16 + srow;
      const short* g = Bp + (size_t)(colBase + rloc) * K2 + kB + schunk;
      __builtin_amdgcn_global_load_lds(
          (const __attribute__((address_space(1))) void*)g,
          (__attribute__((address_space(3))) void*)(&Bs[(w * 32 + j * 16) * 32 + lane * 8]),
          16, 0, 0);
    }
    __syncthreads();  // compiler drains vmcnt before barrier

    frag_ab a[4], b[4];
#pragma unroll
    for (int i = 0; i < 4; ++i)
      a[i] = *(const frag_ab*)&As[(wm + i * 16 + ln) * 32 + q * 8];
#pragma unroll
    for (int j = 0; j < 4; ++j)
      b[j] = *(const frag_ab*)&Bs[(wn + j * 16 + ln) * 32 + q * 8];
#pragma unroll
    for (int i = 0; i < 4; ++i)
#pragma unroll
      for (int j = 0; j < 4; ++j)
        acc[i][j] = __builtin_amdgcn_mfma_f32_16x16x32_bf16(a[i], b[j], acc[i][j], 0, 0, 0);
  }

  // store: D row = q*4 + reg, col = ln (verified m89/m91 mapping)
#pragma unroll
  for (int i = 0; i < 4; ++i) {
    int rowg = rowBase + wm + i * 16 + q * 4;
#pragma unroll
    for (int r = 0; r < 4; ++r) {
      int row = rowg + r;
      if (row < M) {
#pragma unroll
        for (int j = 0; j < 4; ++j) {
          int col = colBase + wn + j * 16 + ln;
          C[(size_t)row * 256 + col] = acc[i][j][r];
        }
      }
    }
  }
}

// ---------- per-(node,head) attention dots: el/er ----------
__global__ __launch_bounds__(256) void eler_kernel(
    const float* __restrict__ feat, const float* __restrict__ al,
    const float* __restrict__ ar, float* __restrict__ el, float* __restrict__ er) {
  int n = blockIdx.x;
  int t = threadIdx.x;
  int h = t >> 6, d = t & 63;
  float v = feat[n * FEAT + t];
  float pl = v * al[h * DD + d];
  float pr = v * ar[h * DD + d];
#pragma unroll
  for (int off = 32; off; off >>= 1) {
    pl += __shfl_down(pl, off);
    pr += __shfl_down(pr, off);
  }
  if (d == 0) {
    el[n * HH + h] = pl;
    er[n * HH + h] = pr;
  }
}

// ---------- CSR build ----------
__global__ __launch_bounds__(256) void hist_kernel(const int* __restrict__ dst,
                                                   int* __restrict__ deg) {
  int e = blockIdx.x * 256 + threadIdx.x;
  if (e < NEDGES) atomicAdd(&deg[dst[e]], 1);
}

__global__ __launch_bounds__(256) void scan_block_kernel(const int* __restrict__ deg,
                                                         int* __restrict__ off,
                                                         int* __restrict__ bsum) {
  __shared__ int tmp[256];
  int b = blockIdx.x, t = threadIdx.x;
  int i = b * 256 + t;
  int v = (i < NNODES) ? deg[i] : 0;
  tmp[t] = v;
  __syncthreads();
  for (int s = 1; s < 256; s <<= 1) {
    int add = (t >= s) ? tmp[t - s] : 0;
    __syncthreads();
    tmp[t] += add;
    __syncthreads();
  }
  if (i < NNODES) off[i + 1] = tmp[t];
  if (t == 255) bsum[b] = tmp[255];
}

__global__ __launch_bounds__(256) void scan_top_kernel(int* __restrict__ bsum) {
  __shared__ int tmp[256];
  int t = threadIdx.x;
  int v = (t < NB) ? bsum[t] : 0;
  tmp[t] = v;
  __syncthreads();
  for (int s = 1; s < 256; s <<= 1) {
    int add = (t >= s) ? tmp[t - s] : 0;
    __syncthreads();
    tmp[t] += add;
    __syncthreads();
  }
  if (t < NB) bsum[t] = tmp[t] - v;
}

__global__ __launch_bounds__(256) void scan_add_kernel(int* __restrict__ off,
                                                       const int* __restrict__ bsum) {
  int b = blockIdx.x, t = threadIdx.x;
  int i = b * 256 + t;
  if (i < NNODES) off[i + 1] += bsum[b];
  if (i == 0) off[0] = 0;
}

__global__ __launch_bounds__(256) void cursor_kernel(const int* __restrict__ off,
                                                     int* __restrict__ cursor) {
  int i = blockIdx.x * 256 + threadIdx.x;
  if (i < NNODES) cursor[i] = off[i];
}

__global__ __launch_bounds__(256) void scatter_kernel(const int* __restrict__ src,
                                                      const int* __restrict__ dst,
                                                      int* __restrict__ cursor,
                                                      int* __restrict__ csr_src) {
  int e = blockIdx.x * 256 + threadIdx.x;
  if (e >= NEDGES) return;
  int d = dst[e];
  int pos = atomicAdd(&cursor[d], 1);
  csr_src[pos] = src[e];
}

// ---------- fused per-dst-node GAT ----------
template <int LAYER>
__global__ __launch_bounds__(256) void gat_agg_kernel(
    const int* __restrict__ off, const int* __restrict__ csr_src,
    const float* __restrict__ el, const float* __restrict__ er,
    const float* __restrict__ feat, float* __restrict__ outp) {
  __shared__ float sh_a[ECAP * HH];  // 8 KB
  __shared__ int sh_s[ECAP];         // 2 KB
  __shared__ float red[256];         // 1 KB
  const int n = blockIdx.x;
  const int t = threadIdx.x;
  const int h = t >> 6;
  const int beg = off[n];
  const int deg = off[n + 1] - beg;
  float v = 0.f;

  if (deg > 0 && deg <= ECAP) {
    const int hh = t & 3, j0 = t >> 2;
    const float erd = er[n * HH + hh];
    float m = -INFINITY;
    for (int j = j0; j < deg; j += 64) {
      int s = csr_src[beg + j];
      if (hh == 0) sh_s[j] = s;
      float e = el[s * HH + hh] + erd;
      e = e > 0.f ? e : 0.2f * e;
      sh_a[j * HH + hh] = e;
      m = fmaxf(m, e);
    }
    red[t] = m;
    __syncthreads();
#pragma unroll
    for (int sft = 128; sft >= 4; sft >>= 1) {
      if (t < sft) red[t] = fmaxf(red[t], red[t + sft]);
      __syncthreads();
    }
    const float mh = red[hh];
    __syncthreads();
    float ps = 0.f;
    for (int j = j0; j < deg; j += 64) {
      float a = __expf(sh_a[j * HH + hh] - mh);
      sh_a[j * HH + hh] = a;
      ps += a;
    }
    red[t] = ps;
    __syncthreads();
#pragma unroll
    for (int sft = 128; sft >= 4; sft >>= 1) {
      if (t < sft) red[t] += red[t + sft];
      __syncthreads();
    }
    const float sv = red[hh];
    const float sinv = sv > 0.f ? 1.f / sv : 0.f;
    for (int j = j0; j < deg; j += 64) sh_a[j * HH + hh] *= sinv;
    __syncthreads();

    float acc = 0.f;
    int j = 0;
    for (; j + 4 <= deg; j += 4) {
      int s0 = sh_s[j], s1 = sh_s[j + 1], s2 = sh_s[j + 2], s3 = sh_s[j + 3];
      float a0 = sh_a[j * HH + h], a1 = sh_a[(j + 1) * HH + h];
      float a2 = sh_a[(j + 2) * HH + h], a3 = sh_a[(j + 3) * HH + h];
      float f0 = feat[(long)s0 * FEAT + t];
      float f1 = feat[(long)s1 * FEAT + t];
      float f2 = feat[(long)s2 * FEAT + t];
      float f3 = feat[(long)s3 * FEAT + t];
      acc = fmaf(a0, f0, acc);
      acc = fmaf(a1, f1, acc);
      acc = fmaf(a2, f2, acc);
      acc = fmaf(a3, f3, acc);
    }
    for (; j < deg; ++j) {
      acc = fmaf(sh_a[j * HH + h], feat[(long)sh_s[j] * FEAT + t], acc);
    }
    v = acc;
  } else if (deg > ECAP) {
    const float erd = er[n * HH + h];
    float m = -INFINITY;
    for (int i = beg; i < beg + deg; ++i) {
      int s = csr_src[i];
      float e = el[s * HH + h] + erd;
      e = e > 0.f ? e : 0.2f * e;
      m = fmaxf(m, e);
    }
    float acc = 0.f, ssum = 0.f;
    for (int i = beg; i < beg + deg; ++i) {
      int s = csr_src[i];
      float e = el[s * HH + h] + erd;
      e = e > 0.f ? e : 0.2f * e;
      float a = __expf(e - m);
      ssum += a;
      acc = fmaf(a, feat[(long)s * FEAT + t], acc);
    }
    v = (ssum > 0.f) ? acc / ssum : 0.f;
  }

  if (LAYER == 1) {
    v = v > 0.f ? v : (__expf(v) - 1.f);  // ELU
    outp[n * FEAT + t] = v;
  } else {
    __syncthreads();
    red[t] = v;
    __syncthreads();
    if (t < DD) {
      float o = 0.25f * (red[t] + red[t + 64] + red[t + 128] + red[t + 192]);
      outp[n * DD + t] = o;
    }
  }
}

extern "C" void kernel_launch(void* const* d_in, const int* in_sizes, int n_in,
                              void* d_out, int out_size, void* d_ws, size_t ws_size,
                              hipStream_t stream) {
  const float* x   = (const float*)d_in[0];
  const int*   src = (const int*)d_in[1];
  const int*   dst = (const int*)d_in[2];
  const float* W1  = (const float*)d_in[3];
  const float* al1 = (const float*)d_in[4];
  const float* ar1 = (const float*)d_in[5];
  const float* W2  = (const float*)d_in[6];
  const float* al2 = (const float*)d_in[7];
  const float* ar2 = (const float*)d_in[8];
  float* out = (float*)d_out;

  // workspace layout
  float* ws = (float*)d_ws;
  float* bufA = ws;                        // NNODES*FEAT : feat (fp32)
  float* bufB = bufA + NNODES * FEAT;      // NNODES*FEAT : h (layer-1 out)
  float* el   = bufB + NNODES * FEAT;
  float* er   = el + NNODES * HH;
  int* deg     = (int*)(er + NNODES * HH);
  int* off     = deg + NNODES;
  int* cursor  = off + NNODES + 1;
  int* bsum    = cursor + NNODES;
  int* csr_src = bsum + 256;
  uintptr_t apAddr = ((uintptr_t)(csr_src + NEDGES) + 63) & ~(uintptr_t)63;
  short* Apr = (short*)apAddr;             // MPAD * 1024 halfs (max 2K)
  short* Bpr = Apr + (size_t)MPAD * 1024;  // 256 * 1024 halfs

  const int edgeBlocks = (NEDGES + 255) / 256;
  dim3 mfmaGrid(MPAD / 128, 2);

  // ---------- CSR build (shared by both layers) ----------
  hipMemsetAsync(deg, 0, NNODES * sizeof(int), stream);
  hist_kernel<<<edgeBlocks, 256, 0, stream>>>(dst, deg);
  scan_block_kernel<<<NB, 256, 0, stream>>>(deg, off, bsum);
  scan_top_kernel<<<1, 256, 0, stream>>>(bsum);
  scan_add_kernel<<<NB, 256, 0, stream>>>(off, bsum);
  cursor_kernel<<<NB, 256, 0, stream>>>(off, cursor);
  scatter_kernel<<<edgeBlocks, 256, 0, stream>>>(src, dst, cursor, csr_src);

  // ---------- layer 1 : K=512 ----------
  split_a_kernel<<<dim3(512 / 256, MPAD), 256, 0, stream>>>(x, Apr, NNODES, 512);
  prep_b_kernel<<<(512 * 256 + 255) / 256, 256, 0, stream>>>(W1, Bpr, 512);
  mfma_gemm_kernel<<<mfmaGrid, 256, 0, stream>>>(Apr, Bpr, bufA, NNODES, 512);
  eler_kernel<<<NNODES, 256, 0, stream>>>(bufA, al1, ar1, el, er);
  gat_agg_kernel<1><<<NNODES, 256, 0, stream>>>(off, csr_src, el, er, bufA, bufB);

  // ---------- layer 2 : K=256 ----------
  split_a_kernel<<<dim3(256 / 256, MPAD), 256, 0, stream>>>(bufB, Apr, NNODES, 256);
  prep_b_kernel<<<(256 * 256 + 255) / 256, 256, 0, stream>>>(W2, Bpr, 256);
  mfma_gemm_kernel<<<mfmaGrid, 256, 0, stream>>>(Apr, Bpr, bufA, NNODES, 256);
  eler_kernel<<<NNODES, 256, 0, stream>>>(bufA, al2, ar2, el, er);
  gat_agg_kernel<2><<<NNODES, 256, 0, stream>>>(off, csr_src, el, er, bufA, out);
}

// Round 5
// 690.193 us; speedup vs baseline: 2.8645x; 1.1325x over previous
//
#include <hip/hip_runtime.h>

#define NNODES 50000
#define NEDGES 800000
#define HH 4
#define DD 64
#define FEAT 256   // HH*DD
#define NB ((NNODES + 255) / 256)
#define ECAP 512
#define APAD 520   // per-head LDS stride (breaks bank alias: 520 % 32 == 8)
#define MPAD 50048 // 391 * 128

typedef __attribute__((ext_vector_type(8))) short frag_ab;   // 8 bf16
typedef __attribute__((ext_vector_type(4))) float frag_cd;   // 4 fp32

// ---------- bf16 helpers (RNE) ----------
__device__ __forceinline__ short f2bf(float v) {
  union { float f; unsigned u; } x; x.f = v;
  unsigned r = x.u + 0x7fffu + ((x.u >> 16) & 1u);
  return (short)(r >> 16);
}
__device__ __forceinline__ float bf2f(short b) {
  union { float f; unsigned u; } x;
  x.u = ((unsigned)(unsigned short)b) << 16;
  return x.f;
}

// ---------- split A (fp32 MxK) -> A' bf16 [MPAD x 2K] = [Ahi | Alo] ----------
__global__ __launch_bounds__(256) void split_a_kernel(
    const float* __restrict__ A, short* __restrict__ Ap, int M, int K) {
  int k = blockIdx.x * 256 + threadIdx.x;
  int m = blockIdx.y;
  float v = (m < M) ? A[(size_t)m * K + k] : 0.f;
  short hi = f2bf(v);
  float lo = v - bf2f(hi);
  size_t base = (size_t)m * 2 * K;
  Ap[base + k] = hi;
  Ap[base + K + k] = f2bf(lo);
}

// ---------- prep B (fp32 KxN, N=256) -> B'^T bf16 [N x 2K] = [Bhi | Blo] ----------
__global__ __launch_bounds__(256) void prep_b_kernel(
    const float* __restrict__ B, short* __restrict__ Bp, int K) {
  int idx = blockIdx.x * 256 + threadIdx.x;
  if (idx >= K * 256) return;
  int k = idx >> 8, n = idx & 255;
  float v = B[idx];
  short hi = f2bf(v);
  float lo = v - bf2f(hi);
  Bp[(size_t)n * 2 * K + k] = hi;
  Bp[(size_t)n * 2 * K + K + k] = f2bf(lo);
}

// ---------- MFMA GEMM + fused el/er epilogue ----------
// C[M,256] = split3(A)@split3(B); el/er[row,h] = C-row dot al/ar (per head).
// 128x128 tile, BK=32, 4 waves (2x2 of 64x64), 16x16x32 bf16 MFMA.
__global__ __launch_bounds__(256) void mfma_gemm_kernel(
    const short* __restrict__ Ap, const short* __restrict__ Bp,
    float* __restrict__ C, const float* __restrict__ al,
    const float* __restrict__ ar, float* __restrict__ elp,
    float* __restrict__ erp, int M, int K) {
  __shared__ short As[128 * 32];  // 8 KB
  __shared__ short Bs[128 * 32];  // 8 KB
  const int tid = threadIdx.x;
  const int w = tid >> 6, lane = tid & 63;
  const int q = lane >> 4, ln = lane & 15;
  const int rowBase = blockIdx.x * 128;
  const int colBase = blockIdx.y * 128;
  const int K2 = 2 * K;
  const int wm = (w >> 1) * 64;
  const int wn = (w & 1) * 64;

  frag_cd acc[4][4] = {};

  const int i1 = K >> 5;
  const int srow = lane >> 2;
  const int schunk = (lane & 3) * 8;

  for (int it = 0; it < 3 * i1; ++it) {
    int s = (it >= i1) + (it >= 2 * i1);
    int ib = it - (s == 1 ? i1 : (s == 2 ? 2 * i1 : 0));
    int kA = (s == 1 ? K : 0) + ib * 32;
    int kB = (s == 2 ? K : 0) + ib * 32;

    __syncthreads();
#pragma unroll
    for (int j = 0; j < 2; ++j) {
      int rloc = w * 32 + j * 16 + srow;
      const short* g = Ap + (size_t)(rowBase + rloc) * K2 + kA + schunk;
      __builtin_amdgcn_global_load_lds(
          (const __attribute__((address_space(1))) void*)g,
          (__attribute__((address_space(3))) void*)(&As[(w * 32 + j * 16) * 32 + lane * 8]),
          16, 0, 0);
    }
#pragma unroll
    for (int j = 0; j < 2; ++j) {
      int rloc = w * 32 + j * 16 + srow;
      const short* g = Bp + (size_t)(colBase + rloc) * K2 + kB + schunk;
      __builtin_amdgcn_global_load_lds(
          (const __attribute__((address_space(1))) void*)g,
          (__attribute__((address_space(3))) void*)(&Bs[(w * 32 + j * 16) * 32 + lane * 8]),
          16, 0, 0);
    }
    __syncthreads();

    frag_ab a[4], b[4];
#pragma unroll
    for (int i = 0; i < 4; ++i)
      a[i] = *(const frag_ab*)&As[(wm + i * 16 + ln) * 32 + q * 8];
#pragma unroll
    for (int j = 0; j < 4; ++j)
      b[j] = *(const frag_ab*)&Bs[(wn + j * 16 + ln) * 32 + q * 8];
#pragma unroll
    for (int i = 0; i < 4; ++i)
#pragma unroll
      for (int j = 0; j < 4; ++j)
        acc[i][j] = __builtin_amdgcn_mfma_f32_16x16x32_bf16(a[i], b[j], acc[i][j], 0, 0, 0);
  }

  // ---- C store (D row = q*4+reg, col = ln; verified m89/m91) ----
#pragma unroll
  for (int i = 0; i < 4; ++i) {
    int rowg = rowBase + wm + i * 16 + q * 4;
#pragma unroll
    for (int r = 0; r < 4; ++r) {
      int row = rowg + r;
      if (row < M) {
#pragma unroll
        for (int j = 0; j < 4; ++j) {
          int col = colBase + wn + j * 16 + ln;
          C[(size_t)row * 256 + col] = acc[i][j][r];
        }
      }
    }
  }

  // ---- fused el/er: this wave's 64 cols == one head ----
  const int h = (colBase + wn) >> 6;
  float alv[4], arv[4];
#pragma unroll
  for (int j = 0; j < 4; ++j) {
    alv[j] = al[h * DD + j * 16 + ln];
    arv[j] = ar[h * DD + j * 16 + ln];
  }
#pragma unroll
  for (int i = 0; i < 4; ++i) {
#pragma unroll
    for (int r = 0; r < 4; ++r) {
      float pl = 0.f, pr = 0.f;
#pragma unroll
      for (int j = 0; j < 4; ++j) {
        pl = fmaf(acc[i][j][r], alv[j], pl);
        pr = fmaf(acc[i][j][r], arv[j], pr);
      }
#pragma unroll
      for (int msk = 1; msk < 16; msk <<= 1) {
        pl += __shfl_xor(pl, msk);
        pr += __shfl_xor(pr, msk);
      }
      int row = rowBase + wm + i * 16 + q * 4 + r;
      if (ln == 0 && row < M) {
        elp[row * HH + h] = pl;
        erp[row * HH + h] = pr;
      }
    }
  }
}

// ---------- CSR build ----------
__global__ __launch_bounds__(256) void hist_kernel(const int* __restrict__ dst,
                                                   int* __restrict__ deg) {
  int e = blockIdx.x * 256 + threadIdx.x;
  if (e < NEDGES) atomicAdd(&deg[dst[e]], 1);
}

__global__ __launch_bounds__(256) void scan_block_kernel(const int* __restrict__ deg,
                                                         int* __restrict__ off,
                                                         int* __restrict__ bsum) {
  __shared__ int tmp[256];
  int b = blockIdx.x, t = threadIdx.x;
  int i = b * 256 + t;
  int v = (i < NNODES) ? deg[i] : 0;
  tmp[t] = v;
  __syncthreads();
  for (int s = 1; s < 256; s <<= 1) {
    int add = (t >= s) ? tmp[t - s] : 0;
    __syncthreads();
    tmp[t] += add;
    __syncthreads();
  }
  if (i < NNODES) off[i + 1] = tmp[t];
  if (t == 255) bsum[b] = tmp[255];
}

__global__ __launch_bounds__(256) void scan_top_kernel(int* __restrict__ bsum) {
  __shared__ int tmp[256];
  int t = threadIdx.x;
  int v = (t < NB) ? bsum[t] : 0;
  tmp[t] = v;
  __syncthreads();
  for (int s = 1; s < 256; s <<= 1) {
    int add = (t >= s) ? tmp[t - s] : 0;
    __syncthreads();
    tmp[t] += add;
    __syncthreads();
  }
  if (t < NB) bsum[t] = tmp[t] - v;
}

__global__ __launch_bounds__(256) void scan_add_kernel(int* __restrict__ off,
                                                       const int* __restrict__ bsum,
                                                       int* __restrict__ cursor) {
  int b = blockIdx.x, t = threadIdx.x;
  int i = b * 256 + t;
  if (i < NNODES) {
    int val = off[i + 1] + bsum[b];
    off[i + 1] = val;
    if (i + 1 < NNODES) cursor[i + 1] = val;
  }
  if (i == 0) { off[0] = 0; cursor[0] = 0; }
}

__global__ __launch_bounds__(256) void scatter_kernel(const int* __restrict__ src,
                                                      const int* __restrict__ dst,
                                                      int* __restrict__ cursor,
                                                      int* __restrict__ csr_src) {
  int e = blockIdx.x * 256 + threadIdx.x;
  if (e >= NEDGES) return;
  int d = dst[e];
  int pos = atomicAdd(&cursor[d], 1);
  csr_src[pos] = src[e];
}

// ---------- fused per-dst-node GAT ----------
// Phase 1: wave w = head w, lane = edge; shfl-butterfly softmax (deg<=64 fast path).
// Phase 2: wave w = edge (j%4==w), lane l = cols 4l..4l+3, float4 gather.
// LAYER 1 writes bf16 [hi|lo] split rows (feeds next GEMM); LAYER 2 writes head-mean.
template <int LAYER>
__global__ __launch_bounds__(256) void gat_agg_kernel(
    const int* __restrict__ off, const int* __restrict__ csr_src,
    const float* __restrict__ el, const float* __restrict__ er,
    const float* __restrict__ feat, float* __restrict__ outp,
    short* __restrict__ outs) {
  __shared__ float sA[HH * APAD];  // 8.3 KB normalized weights, per-head stride APAD
  __shared__ int sS[ECAP];         // 2 KB src ids
  __shared__ float sR[4 * 256];    // 4 KB cross-wave partials
  const int n = blockIdx.x;
  const int t = threadIdx.x;
  const int w = t >> 6;
  const int lane = t & 63;
  const int beg = off[n];
  const int deg = off[n + 1] - beg;
  float v = 0.f;

  if (deg <= ECAP) {
    const float erd = er[n * HH + w];
    if (deg > 0 && deg <= 64) {
      // ---- phase 1 fast path: pure shfl ----
      float e = -INFINITY;
      if (lane < deg) {
        int s = csr_src[beg + lane];
        if (w == 0) sS[lane] = s;
        e = el[s * HH + w] + erd;
        e = e > 0.f ? e : 0.2f * e;
      }
      float m = e;
#pragma unroll
      for (int msk = 32; msk; msk >>= 1) m = fmaxf(m, __shfl_xor(m, msk));
      float a = (lane < deg) ? __expf(e - m) : 0.f;
      float ps = a;
#pragma unroll
      for (int msk = 32; msk; msk >>= 1) ps += __shfl_xor(ps, msk);
      if (lane < deg) sA[w * APAD + lane] = a / ps;
    } else if (deg > 64) {
      // ---- phase 1 generic: LDS two-pass ----
      float m = -INFINITY;
      for (int j = lane; j < deg; j += 64) {
        int s = csr_src[beg + j];
        if (w == 0) sS[j] = s;
        float e = el[s * HH + w] + erd;
        e = e > 0.f ? e : 0.2f * e;
        sA[w * APAD + j] = e;
        m = fmaxf(m, e);
      }
#pragma unroll
      for (int msk = 32; msk; msk >>= 1) m = fmaxf(m, __shfl_xor(m, msk));
      float ps = 0.f;
      for (int j = lane; j < deg; j += 64) {
        float a = __expf(sA[w * APAD + j] - m);
        sA[w * APAD + j] = a;
        ps += a;
      }
#pragma unroll
      for (int msk = 32; msk; msk >>= 1) ps += __shfl_xor(ps, msk);
      float sinv = 1.f / ps;
      for (int j = lane; j < deg; j += 64) sA[w * APAD + j] *= sinv;
    }
    __syncthreads();

    // ---- phase 2: float4 gather, wave per edge ----
    const int h2 = lane >> 4;
    const int cb = lane << 2;
    const float* sAh = &sA[h2 * APAD];
    float ax = 0.f, ay = 0.f, az = 0.f, aw = 0.f;
    int j = w;
    for (; j + 12 < deg; j += 16) {
      int s0 = sS[j], s1 = sS[j + 4], s2 = sS[j + 8], s3 = sS[j + 12];
      float a0 = sAh[j], a1 = sAh[j + 4], a2 = sAh[j + 8], a3 = sAh[j + 12];
      float4 f0 = *(const float4*)&feat[(size_t)s0 * FEAT + cb];
      float4 f1 = *(const float4*)&feat[(size_t)s1 * FEAT + cb];
      float4 f2 = *(const float4*)&feat[(size_t)s2 * FEAT + cb];
      float4 f3 = *(const float4*)&feat[(size_t)s3 * FEAT + cb];
      ax = fmaf(a0, f0.x, ax); ay = fmaf(a0, f0.y, ay); az = fmaf(a0, f0.z, az); aw = fmaf(a0, f0.w, aw);
      ax = fmaf(a1, f1.x, ax); ay = fmaf(a1, f1.y, ay); az = fmaf(a1, f1.z, az); aw = fmaf(a1, f1.w, aw);
      ax = fmaf(a2, f2.x, ax); ay = fmaf(a2, f2.y, ay); az = fmaf(a2, f2.z, az); aw = fmaf(a2, f2.w, aw);
      ax = fmaf(a3, f3.x, ax); ay = fmaf(a3, f3.y, ay); az = fmaf(a3, f3.z, az); aw = fmaf(a3, f3.w, aw);
    }
    for (; j + 4 < deg; j += 8) {
      int s0 = sS[j], s1 = sS[j + 4];
      float a0 = sAh[j], a1 = sAh[j + 4];
      float4 f0 = *(const float4*)&feat[(size_t)s0 * FEAT + cb];
      float4 f1 = *(const float4*)&feat[(size_t)s1 * FEAT + cb];
      ax = fmaf(a0, f0.x, ax); ay = fmaf(a0, f0.y, ay); az = fmaf(a0, f0.z, az); aw = fmaf(a0, f0.w, aw);
      ax = fmaf(a1, f1.x, ax); ay = fmaf(a1, f1.y, ay); az = fmaf(a1, f1.z, az); aw = fmaf(a1, f1.w, aw);
    }
    if (j < deg) {
      int s0 = sS[j];
      float a0 = sAh[j];
      float4 f0 = *(const float4*)&feat[(size_t)s0 * FEAT + cb];
      ax = fmaf(a0, f0.x, ax); ay = fmaf(a0, f0.y, ay); az = fmaf(a0, f0.z, az); aw = fmaf(a0, f0.w, aw);
    }
    float4 accv = make_float4(ax, ay, az, aw);
    *(float4*)&sR[w * 256 + cb] = accv;
    __syncthreads();
    v = sR[t] + sR[256 + t] + sR[512 + t] + sR[768 + t];
  } else {
    // ---- fallback: per-thread recompute (deg > ECAP; unreachable for this graph) ----
    const int h = t >> 6;
    const float erd = er[n * HH + h];
    float m = -INFINITY;
    for (int i = beg; i < beg + deg; ++i) {
      int s = csr_src[i];
      float e = el[s * HH + h] + erd;
      e = e > 0.f ? e : 0.2f * e;
      m = fmaxf(m, e);
    }
    float acc = 0.f, ssum = 0.f;
    for (int i = beg; i < beg + deg; ++i) {
      int s = csr_src[i];
      float e = el[s * HH + h] + erd;
      e = e > 0.f ? e : 0.2f * e;
      float a = __expf(e - m);
      ssum += a;
      acc = fmaf(a, feat[(size_t)s * FEAT + t], acc);
    }
    v = (ssum > 0.f) ? acc / ssum : 0.f;
  }

  // ---- epilogue ----
  if (LAYER == 1) {
    v = v > 0.f ? v : (__expf(v) - 1.f);  // ELU
    short hi = f2bf(v);
    outs[(size_t)n * 512 + t] = hi;
    outs[(size_t)n * 512 + 256 + t] = f2bf(v - bf2f(hi));
  } else {
    __syncthreads();
    sR[t] = v;
    __syncthreads();
    if (t < DD) {
      float o = 0.25f * (sR[t] + sR[t + 64] + sR[t + 128] + sR[t + 192]);
      outp[n * DD + t] = o;
    }
  }
}

extern "C" void kernel_launch(void* const* d_in, const int* in_sizes, int n_in,
                              void* d_out, int out_size, void* d_ws, size_t ws_size,
                              hipStream_t stream) {
  const float* x   = (const float*)d_in[0];
  const int*   src = (const int*)d_in[1];
  const int*   dst = (const int*)d_in[2];
  const float* W1  = (const float*)d_in[3];
  const float* al1 = (const float*)d_in[4];
  const float* ar1 = (const float*)d_in[5];
  const float* W2  = (const float*)d_in[6];
  const float* al2 = (const float*)d_in[7];
  const float* ar2 = (const float*)d_in[8];
  float* out = (float*)d_out;

  // workspace layout
  float* ws = (float*)d_ws;
  float* bufA = ws;                        // NNODES*FEAT : feat (fp32 GEMM out)
  float* el   = bufA + NNODES * FEAT;
  float* er   = el + NNODES * HH;
  int* deg     = (int*)(er + NNODES * HH);
  int* off     = deg + NNODES;
  int* cursor  = off + NNODES + 1;
  int* bsum    = cursor + NNODES;
  int* csr_src = bsum + 256;
  uintptr_t apAddr = ((uintptr_t)(csr_src + NEDGES) + 63) & ~(uintptr_t)63;
  short* Apr = (short*)apAddr;             // MPAD * 1024 halfs (layer1); layer2 uses MPAD*512
  short* Bpr = Apr + (size_t)MPAD * 1024;  // 256 * 1024 halfs

  const int edgeBlocks = (NEDGES + 255) / 256;
  dim3 mfmaGrid(MPAD / 128, 2);

  // ---------- CSR build (shared by both layers) ----------
  hipMemsetAsync(deg, 0, NNODES * sizeof(int), stream);
  hist_kernel<<<edgeBlocks, 256, 0, stream>>>(dst, deg);
  scan_block_kernel<<<NB, 256, 0, stream>>>(deg, off, bsum);
  scan_top_kernel<<<1, 256, 0, stream>>>(bsum);
  scan_add_kernel<<<NB, 256, 0, stream>>>(off, bsum, cursor);
  scatter_kernel<<<edgeBlocks, 256, 0, stream>>>(src, dst, cursor, csr_src);

  // ---------- layer 1 : K=512 ----------
  split_a_kernel<<<dim3(2, MPAD), 256, 0, stream>>>(x, Apr, NNODES, 512);
  prep_b_kernel<<<512, 256, 0, stream>>>(W1, Bpr, 512);
  mfma_gemm_kernel<<<mfmaGrid, 256, 0, stream>>>(Apr, Bpr, bufA, al1, ar1, el, er, NNODES, 512);
  gat_agg_kernel<1><<<NNODES, 256, 0, stream>>>(off, csr_src, el, er, bufA, nullptr, Apr);

  // ---------- layer 2 : K=256 (A' written directly by gat_agg<1>) ----------
  prep_b_kernel<<<256, 256, 0, stream>>>(W2, Bpr, 256);
  mfma_gemm_kernel<<<mfmaGrid, 256, 0, stream>>>(Apr, Bpr, bufA, al2, ar2, el, er, NNODES, 256);
  gat_agg_kernel<2><<<NNODES, 256, 0, stream>>>(off, csr_src, el, er, bufA, out, nullptr);
}

// Round 6
// 689.969 us; speedup vs baseline: 2.8655x; 1.0003x over previous
//
#include <hip/hip_runtime.h>

#define NNODES 50000
#define NEDGES 800000
#define HH 4
#define DD 64
#define FEAT 256   // HH*DD
#define NB ((NNODES + 255) / 256)
#define MPAD 50048 // 391 * 128

typedef __attribute__((ext_vector_type(8))) short frag_ab;   // 8 bf16
typedef __attribute__((ext_vector_type(4))) float frag_cd;   // 4 fp32

// ---------- bf16 helpers (RNE) ----------
__device__ __forceinline__ short f2bf(float v) {
  union { float f; unsigned u; } x; x.f = v;
  unsigned r = x.u + 0x7fffu + ((x.u >> 16) & 1u);
  return (short)(r >> 16);
}
__device__ __forceinline__ float bf2f(short b) {
  union { float f; unsigned u; } x;
  x.u = ((unsigned)(unsigned short)b) << 16;
  return x.f;
}

// ---------- split A (fp32 MxK) -> A' bf16 [MPAD x 2K] = [Ahi | Alo] ----------
__global__ __launch_bounds__(256) void split_a_kernel(
    const float* __restrict__ A, short* __restrict__ Ap, int M, int K) {
  int k = blockIdx.x * 256 + threadIdx.x;
  int m = blockIdx.y;
  float v = (m < M) ? A[(size_t)m * K + k] : 0.f;
  short hi = f2bf(v);
  float lo = v - bf2f(hi);
  size_t base = (size_t)m * 2 * K;
  Ap[base + k] = hi;
  Ap[base + K + k] = f2bf(lo);
}

// ---------- prep B (fp32 KxN, N=256) -> B'^T bf16 [N x 2K] = [Bhi | Blo] ----------
__global__ __launch_bounds__(256) void prep_b_kernel(
    const float* __restrict__ B, short* __restrict__ Bp, int K) {
  int idx = blockIdx.x * 256 + threadIdx.x;
  if (idx >= K * 256) return;
  int k = idx >> 8, n = idx & 255;
  float v = B[idx];
  short hi = f2bf(v);
  float lo = v - bf2f(hi);
  Bp[(size_t)n * 2 * K + k] = hi;
  Bp[(size_t)n * 2 * K + K + k] = f2bf(lo);
}

// ---------- MFMA GEMM + fused el/er epilogue ----------
__global__ __launch_bounds__(256) void mfma_gemm_kernel(
    const short* __restrict__ Ap, const short* __restrict__ Bp,
    float* __restrict__ C, const float* __restrict__ al,
    const float* __restrict__ ar, float* __restrict__ elp,
    float* __restrict__ erp, int M, int K) {
  __shared__ short As[128 * 32];  // 8 KB
  __shared__ short Bs[128 * 32];  // 8 KB
  const int tid = threadIdx.x;
  const int w = tid >> 6, lane = tid & 63;
  const int q = lane >> 4, ln = lane & 15;
  const int rowBase = blockIdx.x * 128;
  const int colBase = blockIdx.y * 128;
  const int K2 = 2 * K;
  const int wm = (w >> 1) * 64;
  const int wn = (w & 1) * 64;

  frag_cd acc[4][4] = {};

  const int i1 = K >> 5;
  const int srow = lane >> 2;
  const int schunk = (lane & 3) * 8;

  for (int it = 0; it < 3 * i1; ++it) {
    int s = (it >= i1) + (it >= 2 * i1);
    int ib = it - (s == 1 ? i1 : (s == 2 ? 2 * i1 : 0));
    int kA = (s == 1 ? K : 0) + ib * 32;
    int kB = (s == 2 ? K : 0) + ib * 32;

    __syncthreads();
#pragma unroll
    for (int j = 0; j < 2; ++j) {
      int rloc = w * 32 + j * 16 + srow;
      const short* g = Ap + (size_t)(rowBase + rloc) * K2 + kA + schunk;
      __builtin_amdgcn_global_load_lds(
          (const __attribute__((address_space(1))) void*)g,
          (__attribute__((address_space(3))) void*)(&As[(w * 32 + j * 16) * 32 + lane * 8]),
          16, 0, 0);
    }
#pragma unroll
    for (int j = 0; j < 2; ++j) {
      int rloc = w * 32 + j * 16 + srow;
      const short* g = Bp + (size_t)(colBase + rloc) * K2 + kB + schunk;
      __builtin_amdgcn_global_load_lds(
          (const __attribute__((address_space(1))) void*)g,
          (__attribute__((address_space(3))) void*)(&Bs[(w * 32 + j * 16) * 32 + lane * 8]),
          16, 0, 0);
    }
    __syncthreads();

    frag_ab a[4], b[4];
#pragma unroll
    for (int i = 0; i < 4; ++i)
      a[i] = *(const frag_ab*)&As[(wm + i * 16 + ln) * 32 + q * 8];
#pragma unroll
    for (int j = 0; j < 4; ++j)
      b[j] = *(const frag_ab*)&Bs[(wn + j * 16 + ln) * 32 + q * 8];
#pragma unroll
    for (int i = 0; i < 4; ++i)
#pragma unroll
      for (int j = 0; j < 4; ++j)
        acc[i][j] = __builtin_amdgcn_mfma_f32_16x16x32_bf16(a[i], b[j], acc[i][j], 0, 0, 0);
  }

  // ---- C store (D row = q*4+reg, col = ln) ----
#pragma unroll
  for (int i = 0; i < 4; ++i) {
    int rowg = rowBase + wm + i * 16 + q * 4;
#pragma unroll
    for (int r = 0; r < 4; ++r) {
      int row = rowg + r;
      if (row < M) {
#pragma unroll
        for (int j = 0; j < 4; ++j) {
          int col = colBase + wn + j * 16 + ln;
          C[(size_t)row * 256 + col] = acc[i][j][r];
        }
      }
    }
  }

  // ---- fused el/er: this wave's 64 cols == one head ----
  const int h = (colBase + wn) >> 6;
  float alv[4], arv[4];
#pragma unroll
  for (int j = 0; j < 4; ++j) {
    alv[j] = al[h * DD + j * 16 + ln];
    arv[j] = ar[h * DD + j * 16 + ln];
  }
#pragma unroll
  for (int i = 0; i < 4; ++i) {
#pragma unroll
    for (int r = 0; r < 4; ++r) {
      float pl = 0.f, pr = 0.f;
#pragma unroll
      for (int j = 0; j < 4; ++j) {
        pl = fmaf(acc[i][j][r], alv[j], pl);
        pr = fmaf(acc[i][j][r], arv[j], pr);
      }
#pragma unroll
      for (int msk = 1; msk < 16; msk <<= 1) {
        pl += __shfl_xor(pl, msk);
        pr += __shfl_xor(pr, msk);
      }
      int row = rowBase + wm + i * 16 + q * 4 + r;
      if (ln == 0 && row < M) {
        elp[row * HH + h] = pl;
        erp[row * HH + h] = pr;
      }
    }
  }
}

// ---------- CSR build ----------
__global__ __launch_bounds__(256) void hist_kernel(const int* __restrict__ dst,
                                                   int* __restrict__ deg) {
  int e = blockIdx.x * 256 + threadIdx.x;
  if (e < NEDGES) atomicAdd(&deg[dst[e]], 1);
}

__global__ __launch_bounds__(256) void scan_block_kernel(const int* __restrict__ deg,
                                                         int* __restrict__ off,
                                                         int* __restrict__ bsum) {
  __shared__ int tmp[256];
  int b = blockIdx.x, t = threadIdx.x;
  int i = b * 256 + t;
  int v = (i < NNODES) ? deg[i] : 0;
  tmp[t] = v;
  __syncthreads();
  for (int s = 1; s < 256; s <<= 1) {
    int add = (t >= s) ? tmp[t - s] : 0;
    __syncthreads();
    tmp[t] += add;
    __syncthreads();
  }
  if (i < NNODES) off[i + 1] = tmp[t];
  if (t == 255) bsum[b] = tmp[255];
}

__global__ __launch_bounds__(256) void scan_top_kernel(int* __restrict__ bsum) {
  __shared__ int tmp[256];
  int t = threadIdx.x;
  int v = (t < NB) ? bsum[t] : 0;
  tmp[t] = v;
  __syncthreads();
  for (int s = 1; s < 256; s <<= 1) {
    int add = (t >= s) ? tmp[t - s] : 0;
    __syncthreads();
    tmp[t] += add;
    __syncthreads();
  }
  if (t < NB) bsum[t] = tmp[t] - v;
}

__global__ __launch_bounds__(256) void scan_add_kernel(int* __restrict__ off,
                                                       const int* __restrict__ bsum,
                                                       int* __restrict__ cursor) {
  int b = blockIdx.x, t = threadIdx.x;
  int i = b * 256 + t;
  if (i < NNODES) {
    int val = off[i + 1] + bsum[b];
    off[i + 1] = val;
    if (i + 1 < NNODES) cursor[i + 1] = val;
  }
  if (i == 0) { off[0] = 0; cursor[0] = 0; }
}

__global__ __launch_bounds__(256) void scatter_kernel(const int* __restrict__ src,
                                                      const int* __restrict__ dst,
                                                      int* __restrict__ cursor,
                                                      int* __restrict__ csr_src) {
  int e = blockIdx.x * 256 + threadIdx.x;
  if (e >= NEDGES) return;
  int d = dst[e];
  int pos = atomicAdd(&cursor[d], 1);
  csr_src[pos] = src[e];
}

// ---------- fused per-dst-node GAT: one WAVE per node, no barriers ----------
// Fast path (deg<=64): phase 1 lane=(edge j=lane>>2, head=lane&3), scores once,
// shfl_xor{4,8,16,32} reductions, normalized weights to per-wave LDS slice.
// Phase 2: lane covers cols 4l..4l+3 (head=l>>4); per edge: LDS broadcasts +
// coalesced 1KB float4 gather + FMA, unrolled x4.
// LAYER 1 writes bf16 [hi|lo] split rows; LAYER 2 head-mean via shfl_xor{16,32}.
template <int LAYER>
__global__ __launch_bounds__(256) void gat_agg_kernel(
    const int* __restrict__ off, const int* __restrict__ csr_src,
    const float* __restrict__ el, const float* __restrict__ er,
    const float* __restrict__ feat, float* __restrict__ outp,
    short* __restrict__ outs) {
  __shared__ float sA[4][HH][68];  // [wave][head][edge] normalized weights
  __shared__ int sS[4][64];        // [wave][edge] src ids
  const int w = threadIdx.x >> 6;
  const int lane = threadIdx.x & 63;
  const int n = blockIdx.x * 4 + w;   // NNODES = 4 * 12500 exactly
  const int beg = off[n];
  const int deg = off[n + 1] - beg;

  float4 accv = make_float4(0.f, 0.f, 0.f, 0.f);
  const int h2 = lane >> 4;
  const int cb = lane << 2;

  if (deg > 0 && deg <= 64) {
    // ---- phase 1 ----
    const int h1 = lane & 3, j1 = lane >> 2;
    const float erd = er[n * HH + h1];
    float e[4], a[4];
    float m = -INFINITY;
#pragma unroll
    for (int p = 0; p < 4; ++p) {
      int j = j1 + p * 16;
      float ev = -INFINITY;
      if (j < deg) {
        int s = csr_src[beg + j];
        if (h1 == 0) sS[w][j] = s;
        ev = el[s * HH + h1] + erd;
        ev = ev > 0.f ? ev : 0.2f * ev;
      }
      e[p] = ev;
      m = fmaxf(m, ev);
    }
#pragma unroll
    for (int msk = 4; msk <= 32; msk <<= 1) m = fmaxf(m, __shfl_xor(m, msk));
    float ps = 0.f;
#pragma unroll
    for (int p = 0; p < 4; ++p) {
      a[p] = (j1 + p * 16 < deg) ? __expf(e[p] - m) : 0.f;
      ps += a[p];
    }
#pragma unroll
    for (int msk = 4; msk <= 32; msk <<= 1) ps += __shfl_xor(ps, msk);
    const float sinv = 1.f / ps;
#pragma unroll
    for (int p = 0; p < 4; ++p) {
      int j = j1 + p * 16;
      if (j < deg) sA[w][h1][j] = a[p] * sinv;
    }

    // ---- phase 2: gather (same-wave LDS RAW; compiler inserts lgkmcnt) ----
    int j = 0;
    for (; j + 4 <= deg; j += 4) {
      int s0 = sS[w][j], s1 = sS[w][j + 1], s2 = sS[w][j + 2], s3 = sS[w][j + 3];
      float a0 = sA[w][h2][j], a1 = sA[w][h2][j + 1];
      float a2 = sA[w][h2][j + 2], a3 = sA[w][h2][j + 3];
      float4 f0 = *(const float4*)&feat[(size_t)s0 * FEAT + cb];
      float4 f1 = *(const float4*)&feat[(size_t)s1 * FEAT + cb];
      float4 f2 = *(const float4*)&feat[(size_t)s2 * FEAT + cb];
      float4 f3 = *(const float4*)&feat[(size_t)s3 * FEAT + cb];
      accv.x = fmaf(a0, f0.x, accv.x); accv.y = fmaf(a0, f0.y, accv.y);
      accv.z = fmaf(a0, f0.z, accv.z); accv.w = fmaf(a0, f0.w, accv.w);
      accv.x = fmaf(a1, f1.x, accv.x); accv.y = fmaf(a1, f1.y, accv.y);
      accv.z = fmaf(a1, f1.z, accv.z); accv.w = fmaf(a1, f1.w, accv.w);
      accv.x = fmaf(a2, f2.x, accv.x); accv.y = fmaf(a2, f2.y, accv.y);
      accv.z = fmaf(a2, f2.z, accv.z); accv.w = fmaf(a2, f2.w, accv.w);
      accv.x = fmaf(a3, f3.x, accv.x); accv.y = fmaf(a3, f3.y, accv.y);
      accv.z = fmaf(a3, f3.z, accv.z); accv.w = fmaf(a3, f3.w, accv.w);
    }
    for (; j < deg; ++j) {
      int s0 = sS[w][j];
      float a0 = sA[w][h2][j];
      float4 f0 = *(const float4*)&feat[(size_t)s0 * FEAT + cb];
      accv.x = fmaf(a0, f0.x, accv.x); accv.y = fmaf(a0, f0.y, accv.y);
      accv.z = fmaf(a0, f0.z, accv.z); accv.w = fmaf(a0, f0.w, accv.w);
    }
  } else if (deg > 64) {
    // ---- generic register-only 3-pass fallback (unreachable for Poisson(16)) ----
    const int h1 = lane & 3, j1 = lane >> 2;
    const float erd = er[n * HH + h1];
    float m = -INFINITY;
    for (int j = j1; j < deg; j += 16) {
      int s = csr_src[beg + j];
      float ev = el[s * HH + h1] + erd;
      ev = ev > 0.f ? ev : 0.2f * ev;
      m = fmaxf(m, ev);
    }
#pragma unroll
    for (int msk = 4; msk <= 32; msk <<= 1) m = fmaxf(m, __shfl_xor(m, msk));
    float ps = 0.f;
    for (int j = j1; j < deg; j += 16) {
      int s = csr_src[beg + j];
      float ev = el[s * HH + h1] + erd;
      ev = ev > 0.f ? ev : 0.2f * ev;
      ps += __expf(ev - m);
    }
#pragma unroll
    for (int msk = 4; msk <= 32; msk <<= 1) ps += __shfl_xor(ps, msk);
    const float m2 = __shfl(m, h2);
    const float psinv2 = 1.f / __shfl(ps, h2);
    const float erd2 = er[n * HH + h2];
    for (int j = 0; j < deg; ++j) {
      int s = csr_src[beg + j];
      float ev = el[s * HH + h2] + erd2;
      ev = ev > 0.f ? ev : 0.2f * ev;
      float a0 = __expf(ev - m2) * psinv2;
      float4 f0 = *(const float4*)&feat[(size_t)s * FEAT + cb];
      accv.x = fmaf(a0, f0.x, accv.x); accv.y = fmaf(a0, f0.y, accv.y);
      accv.z = fmaf(a0, f0.z, accv.z); accv.w = fmaf(a0, f0.w, accv.w);
    }
  }

  // ---- epilogue ----
  if (LAYER == 1) {
    float vv[4] = {accv.x, accv.y, accv.z, accv.w};
    short hi4[4], lo4[4];
#pragma unroll
    for (int c = 0; c < 4; ++c) {
      float v = vv[c];
      v = v > 0.f ? v : (__expf(v) - 1.f);  // ELU
      short hi = f2bf(v);
      hi4[c] = hi;
      lo4[c] = f2bf(v - bf2f(hi));
    }
    *(short4*)&outs[(size_t)n * 512 + cb] = make_short4(hi4[0], hi4[1], hi4[2], hi4[3]);
    *(short4*)&outs[(size_t)n * 512 + 256 + cb] = make_short4(lo4[0], lo4[1], lo4[2], lo4[3]);
  } else {
#pragma unroll
    for (int msk = 16; msk <= 32; msk <<= 1) {
      accv.x += __shfl_xor(accv.x, msk);
      accv.y += __shfl_xor(accv.y, msk);
      accv.z += __shfl_xor(accv.z, msk);
      accv.w += __shfl_xor(accv.w, msk);
    }
    if (lane < 16) {
      float4 o = make_float4(0.25f * accv.x, 0.25f * accv.y,
                             0.25f * accv.z, 0.25f * accv.w);
      *(float4*)&outp[(size_t)n * DD + (lane << 2)] = o;
    }
  }
}

extern "C" void kernel_launch(void* const* d_in, const int* in_sizes, int n_in,
                              void* d_out, int out_size, void* d_ws, size_t ws_size,
                              hipStream_t stream) {
  const float* x   = (const float*)d_in[0];
  const int*   src = (const int*)d_in[1];
  const int*   dst = (const int*)d_in[2];
  const float* W1  = (const float*)d_in[3];
  const float* al1 = (const float*)d_in[4];
  const float* ar1 = (const float*)d_in[5];
  const float* W2  = (const float*)d_in[6];
  const float* al2 = (const float*)d_in[7];
  const float* ar2 = (const float*)d_in[8];
  float* out = (float*)d_out;

  // workspace layout
  float* ws = (float*)d_ws;
  float* bufA = ws;                        // NNODES*FEAT : feat (fp32 GEMM out)
  float* el   = bufA + NNODES * FEAT;
  float* er   = el + NNODES * HH;
  int* deg     = (int*)(er + NNODES * HH);
  int* off     = deg + NNODES;
  int* cursor  = off + NNODES + 1;
  int* bsum    = cursor + NNODES;
  int* csr_src = bsum + 256;
  uintptr_t apAddr = ((uintptr_t)(csr_src + NEDGES) + 63) & ~(uintptr_t)63;
  short* Apr = (short*)apAddr;             // MPAD * 1024 halfs
  short* Bpr = Apr + (size_t)MPAD * 1024;  // 256 * 1024 halfs

  const int edgeBlocks = (NEDGES + 255) / 256;
  dim3 mfmaGrid(MPAD / 128, 2);

  // ---------- CSR build (shared by both layers) ----------
  hipMemsetAsync(deg, 0, NNODES * sizeof(int), stream);
  hist_kernel<<<edgeBlocks, 256, 0, stream>>>(dst, deg);
  scan_block_kernel<<<NB, 256, 0, stream>>>(deg, off, bsum);
  scan_top_kernel<<<1, 256, 0, stream>>>(bsum);
  scan_add_kernel<<<NB, 256, 0, stream>>>(off, bsum, cursor);
  scatter_kernel<<<edgeBlocks, 256, 0, stream>>>(src, dst, cursor, csr_src);

  // ---------- layer 1 : K=512 ----------
  split_a_kernel<<<dim3(2, MPAD), 256, 0, stream>>>(x, Apr, NNODES, 512);
  prep_b_kernel<<<512, 256, 0, stream>>>(W1, Bpr, 512);
  mfma_gemm_kernel<<<mfmaGrid, 256, 0, stream>>>(Apr, Bpr, bufA, al1, ar1, el, er, NNODES, 512);
  gat_agg_kernel<1><<<NNODES / 4, 256, 0, stream>>>(off, csr_src, el, er, bufA, nullptr, Apr);

  // ---------- layer 2 : K=256 (A' written directly by gat_agg<1>) ----------
  prep_b_kernel<<<256, 256, 0, stream>>>(W2, Bpr, 256);
  mfma_gemm_kernel<<<mfmaGrid, 256, 0, stream>>>(Apr, Bpr, bufA, al2, ar2, el, er, NNODES, 256);
  gat_agg_kernel<2><<<NNODES / 4, 256, 0, stream>>>(off, csr_src, el, er, bufA, out, nullptr);
}

// Round 7
// 543.237 us; speedup vs baseline: 3.6394x; 1.2701x over previous
//
#include <hip/hip_runtime.h>

#define NNODES 50000
#define NEDGES 800000
#define HH 4
#define DD 64
#define FEAT 256   // HH*DD
#define NB ((NNODES + 255) / 256)
#define MPAD 50048 // 391 * 128

typedef __attribute__((ext_vector_type(8))) short frag_ab;   // 8 bf16
typedef __attribute__((ext_vector_type(4))) float frag_cd;   // 4 fp32

// ---------- bf16 helpers (RNE) ----------
__device__ __forceinline__ short f2bf(float v) {
  union { float f; unsigned u; } x; x.f = v;
  unsigned r = x.u + 0x7fffu + ((x.u >> 16) & 1u);
  return (short)(r >> 16);
}
__device__ __forceinline__ float bf2f(short b) {
  union { float f; unsigned u; } x;
  x.u = ((unsigned)(unsigned short)b) << 16;
  return x.f;
}
__device__ __forceinline__ float bfu2f(unsigned short b) {
  union { float f; unsigned u; } x;
  x.u = ((unsigned)b) << 16;
  return x.f;
}

// ---------- split A (fp32 [M,512]) -> A' bf16 [MPAD x 1024] = [Ahi | Alo] ----------
// float4 in, short4 x2 out. K hardcoded 512 (layer 1 only).
__global__ __launch_bounds__(256) void split_a_kernel(
    const float* __restrict__ A, short* __restrict__ Ap, int M) {
  int id = blockIdx.x * 256 + threadIdx.x;  // MPAD*128 total
  int m = id >> 7;
  int k4 = (id & 127) << 2;
  float4 v = make_float4(0.f, 0.f, 0.f, 0.f);
  if (m < M) v = *(const float4*)&A[(size_t)m * 512 + k4];
  short4 hi, lo;
  hi.x = f2bf(v.x); lo.x = f2bf(v.x - bf2f(hi.x));
  hi.y = f2bf(v.y); lo.y = f2bf(v.y - bf2f(hi.y));
  hi.z = f2bf(v.z); lo.z = f2bf(v.z - bf2f(hi.z));
  hi.w = f2bf(v.w); lo.w = f2bf(v.w - bf2f(hi.w));
  *(short4*)&Ap[(size_t)m * 1024 + k4] = hi;
  *(short4*)&Ap[(size_t)m * 1024 + 512 + k4] = lo;
}

// ---------- prep both B matrices in one launch ----------
// W1: [512,256] -> Bp1 [256 x 1024]; W2: [256,256] -> Bp2 [256 x 512] (B^T [hi|lo])
__global__ __launch_bounds__(256) void prep_b_kernel(
    const float* __restrict__ W1, const float* __restrict__ W2,
    short* __restrict__ Bp1, short* __restrict__ Bp2) {
  int idx = blockIdx.x * 256 + threadIdx.x;  // 768 blocks = (512+256)*256
  const float* B; short* Bp; int K;
  if (idx < 512 * 256) { B = W1; Bp = Bp1; K = 512; }
  else { idx -= 512 * 256; B = W2; Bp = Bp2; K = 256; }
  int k = idx >> 8, n = idx & 255;
  float v = B[idx];
  short hi = f2bf(v);
  float lo = v - bf2f(hi);
  Bp[(size_t)n * 2 * K + k] = hi;
  Bp[(size_t)n * 2 * K + K + k] = f2bf(lo);
}

// ---------- MFMA GEMM -> bf16 feat + fused el/er epilogue ----------
// featb[M,256] bf16 = round(split3(A)@split3(B)); el/er from exact fp32 accs.
__global__ __launch_bounds__(256) void mfma_gemm_kernel(
    const short* __restrict__ Ap, const short* __restrict__ Bp,
    unsigned short* __restrict__ featb, const float* __restrict__ al,
    const float* __restrict__ ar, float* __restrict__ elp,
    float* __restrict__ erp, int M, int K) {
  __shared__ short As[128 * 32];  // 8 KB
  __shared__ short Bs[128 * 32];  // 8 KB
  const int tid = threadIdx.x;
  const int w = tid >> 6, lane = tid & 63;
  const int q = lane >> 4, ln = lane & 15;
  const int rowBase = blockIdx.x * 128;
  const int colBase = blockIdx.y * 128;
  const int K2 = 2 * K;
  const int wm = (w >> 1) * 64;
  const int wn = (w & 1) * 64;

  frag_cd acc[4][4] = {};

  const int i1 = K >> 5;
  const int srow = lane >> 2;
  const int schunk = (lane & 3) * 8;

  for (int it = 0; it < 3 * i1; ++it) {
    int s = (it >= i1) + (it >= 2 * i1);
    int ib = it - (s == 1 ? i1 : (s == 2 ? 2 * i1 : 0));
    int kA = (s == 1 ? K : 0) + ib * 32;
    int kB = (s == 2 ? K : 0) + ib * 32;

    __syncthreads();
#pragma unroll
    for (int j = 0; j < 2; ++j) {
      int rloc = w * 32 + j * 16 + srow;
      const short* g = Ap + (size_t)(rowBase + rloc) * K2 + kA + schunk;
      __builtin_amdgcn_global_load_lds(
          (const __attribute__((address_space(1))) void*)g,
          (__attribute__((address_space(3))) void*)(&As[(w * 32 + j * 16) * 32 + lane * 8]),
          16, 0, 0);
    }
#pragma unroll
    for (int j = 0; j < 2; ++j) {
      int rloc = w * 32 + j * 16 + srow;
      const short* g = Bp + (size_t)(colBase + rloc) * K2 + kB + schunk;
      __builtin_amdgcn_global_load_lds(
          (const __attribute__((address_space(1))) void*)g,
          (__attribute__((address_space(3))) void*)(&Bs[(w * 32 + j * 16) * 32 + lane * 8]),
          16, 0, 0);
    }
    __syncthreads();

    frag_ab a[4], b[4];
#pragma unroll
    for (int i = 0; i < 4; ++i)
      a[i] = *(const frag_ab*)&As[(wm + i * 16 + ln) * 32 + q * 8];
#pragma unroll
    for (int j = 0; j < 4; ++j)
      b[j] = *(const frag_ab*)&Bs[(wn + j * 16 + ln) * 32 + q * 8];
#pragma unroll
    for (int i = 0; i < 4; ++i)
#pragma unroll
      for (int j = 0; j < 4; ++j)
        acc[i][j] = __builtin_amdgcn_mfma_f32_16x16x32_bf16(a[i], b[j], acc[i][j], 0, 0, 0);
  }

  // ---- bf16 feat store (D row = q*4+reg, col = ln) ----
#pragma unroll
  for (int i = 0; i < 4; ++i) {
    int rowg = rowBase + wm + i * 16 + q * 4;
#pragma unroll
    for (int r = 0; r < 4; ++r) {
      int row = rowg + r;
      if (row < M) {
#pragma unroll
        for (int j = 0; j < 4; ++j) {
          int col = colBase + wn + j * 16 + ln;
          featb[(size_t)row * 256 + col] = (unsigned short)f2bf(acc[i][j][r]);
        }
      }
    }
  }

  // ---- fused el/er: this wave's 64 cols == one head (exact fp32) ----
  const int h = (colBase + wn) >> 6;
  float alv[4], arv[4];
#pragma unroll
  for (int j = 0; j < 4; ++j) {
    alv[j] = al[h * DD + j * 16 + ln];
    arv[j] = ar[h * DD + j * 16 + ln];
  }
#pragma unroll
  for (int i = 0; i < 4; ++i) {
#pragma unroll
    for (int r = 0; r < 4; ++r) {
      float pl = 0.f, pr = 0.f;
#pragma unroll
      for (int j = 0; j < 4; ++j) {
        pl = fmaf(acc[i][j][r], alv[j], pl);
        pr = fmaf(acc[i][j][r], arv[j], pr);
      }
#pragma unroll
      for (int msk = 1; msk < 16; msk <<= 1) {
        pl += __shfl_xor(pl, msk);
        pr += __shfl_xor(pr, msk);
      }
      int row = rowBase + wm + i * 16 + q * 4 + r;
      if (ln == 0 && row < M) {
        elp[row * HH + h] = pl;
        erp[row * HH + h] = pr;
      }
    }
  }
}

// ---------- CSR build ----------
__global__ __launch_bounds__(256) void hist_kernel(const int* __restrict__ dst,
                                                   int* __restrict__ deg) {
  int e = blockIdx.x * 256 + threadIdx.x;
  if (e < NEDGES) atomicAdd(&deg[dst[e]], 1);
}

__global__ __launch_bounds__(256) void scan_block_kernel(const int* __restrict__ deg,
                                                         int* __restrict__ off,
                                                         int* __restrict__ bsum) {
  __shared__ int tmp[256];
  int b = blockIdx.x, t = threadIdx.x;
  int i = b * 256 + t;
  int v = (i < NNODES) ? deg[i] : 0;
  tmp[t] = v;
  __syncthreads();
  for (int s = 1; s < 256; s <<= 1) {
    int add = (t >= s) ? tmp[t - s] : 0;
    __syncthreads();
    tmp[t] += add;
    __syncthreads();
  }
  if (i < NNODES) off[i + 1] = tmp[t];
  if (t == 255) bsum[b] = tmp[255];
}

__global__ __launch_bounds__(256) void scan_top_kernel(int* __restrict__ bsum) {
  __shared__ int tmp[256];
  int t = threadIdx.x;
  int v = (t < NB) ? bsum[t] : 0;
  tmp[t] = v;
  __syncthreads();
  for (int s = 1; s < 256; s <<= 1) {
    int add = (t >= s) ? tmp[t - s] : 0;
    __syncthreads();
    tmp[t] += add;
    __syncthreads();
  }
  if (t < NB) bsum[t] = tmp[t] - v;
}

__global__ __launch_bounds__(256) void scan_add_kernel(int* __restrict__ off,
                                                       const int* __restrict__ bsum,
                                                       int* __restrict__ cursor) {
  int b = blockIdx.x, t = threadIdx.x;
  int i = b * 256 + t;
  if (i < NNODES) {
    int val = off[i + 1] + bsum[b];
    off[i + 1] = val;
    if (i + 1 < NNODES) cursor[i + 1] = val;
  }
  if (i == 0) { off[0] = 0; cursor[0] = 0; }
}

__global__ __launch_bounds__(256) void scatter_kernel(const int* __restrict__ src,
                                                      const int* __restrict__ dst,
                                                      int* __restrict__ cursor,
                                                      int* __restrict__ csr_src) {
  int e = blockIdx.x * 256 + threadIdx.x;
  if (e >= NEDGES) return;
  int d = dst[e];
  int pos = atomicAdd(&cursor[d], 1);
  csr_src[pos] = src[e];
}

// ---------- fused per-dst-node GAT: one WAVE per node, bf16 gather ----------
template <int LAYER>
__global__ __launch_bounds__(256) void gat_agg_kernel(
    const int* __restrict__ off, const int* __restrict__ csr_src,
    const float* __restrict__ el, const float* __restrict__ er,
    const unsigned short* __restrict__ featb, float* __restrict__ outp,
    short* __restrict__ outs) {
  __shared__ float sA[4][HH][68];  // [wave][head][edge] normalized weights
  __shared__ int sS[4][64];        // [wave][edge] src ids
  const int w = threadIdx.x >> 6;
  const int lane = threadIdx.x & 63;
  const int n = blockIdx.x * 4 + w;   // NNODES = 4 * 12500 exactly
  const int beg = off[n];
  const int deg = off[n + 1] - beg;

  float4 accv = make_float4(0.f, 0.f, 0.f, 0.f);
  const int h2 = lane >> 4;
  const int cb = lane << 2;

  if (deg > 0 && deg <= 64) {
    // ---- phase 1: scores once per (edge,head), shfl reductions ----
    const int h1 = lane & 3, j1 = lane >> 2;
    const float erd = er[n * HH + h1];
    float e[4], a[4];
    float m = -INFINITY;
#pragma unroll
    for (int p = 0; p < 4; ++p) {
      int j = j1 + p * 16;
      float ev = -INFINITY;
      if (j < deg) {
        int s = csr_src[beg + j];
        if (h1 == 0) sS[w][j] = s;
        ev = el[s * HH + h1] + erd;
        ev = ev > 0.f ? ev : 0.2f * ev;
      }
      e[p] = ev;
      m = fmaxf(m, ev);
    }
#pragma unroll
    for (int msk = 4; msk <= 32; msk <<= 1) m = fmaxf(m, __shfl_xor(m, msk));
    float ps = 0.f;
#pragma unroll
    for (int p = 0; p < 4; ++p) {
      a[p] = (j1 + p * 16 < deg) ? __expf(e[p] - m) : 0.f;
      ps += a[p];
    }
#pragma unroll
    for (int msk = 4; msk <= 32; msk <<= 1) ps += __shfl_xor(ps, msk);
    const float sinv = 1.f / ps;
#pragma unroll
    for (int p = 0; p < 4; ++p) {
      int j = j1 + p * 16;
      if (j < deg) sA[w][h1][j] = a[p] * sinv;
    }

    // ---- phase 2: bf16 gather (512 B/wave per edge), unrolled x4 ----
    int j = 0;
    for (; j + 4 <= deg; j += 4) {
      int s0 = sS[w][j], s1 = sS[w][j + 1], s2 = sS[w][j + 2], s3 = sS[w][j + 3];
      float a0 = sA[w][h2][j], a1 = sA[w][h2][j + 1];
      float a2 = sA[w][h2][j + 2], a3 = sA[w][h2][j + 3];
      ushort4 u0 = *(const ushort4*)&featb[(size_t)s0 * FEAT + cb];
      ushort4 u1 = *(const ushort4*)&featb[(size_t)s1 * FEAT + cb];
      ushort4 u2 = *(const ushort4*)&featb[(size_t)s2 * FEAT + cb];
      ushort4 u3 = *(const ushort4*)&featb[(size_t)s3 * FEAT + cb];
      accv.x = fmaf(a0, bfu2f(u0.x), accv.x); accv.y = fmaf(a0, bfu2f(u0.y), accv.y);
      accv.z = fmaf(a0, bfu2f(u0.z), accv.z); accv.w = fmaf(a0, bfu2f(u0.w), accv.w);
      accv.x = fmaf(a1, bfu2f(u1.x), accv.x); accv.y = fmaf(a1, bfu2f(u1.y), accv.y);
      accv.z = fmaf(a1, bfu2f(u1.z), accv.z); accv.w = fmaf(a1, bfu2f(u1.w), accv.w);
      accv.x = fmaf(a2, bfu2f(u2.x), accv.x); accv.y = fmaf(a2, bfu2f(u2.y), accv.y);
      accv.z = fmaf(a2, bfu2f(u2.z), accv.z); accv.w = fmaf(a2, bfu2f(u2.w), accv.w);
      accv.x = fmaf(a3, bfu2f(u3.x), accv.x); accv.y = fmaf(a3, bfu2f(u3.y), accv.y);
      accv.z = fmaf(a3, bfu2f(u3.z), accv.z); accv.w = fmaf(a3, bfu2f(u3.w), accv.w);
    }
    for (; j < deg; ++j) {
      int s0 = sS[w][j];
      float a0 = sA[w][h2][j];
      ushort4 u0 = *(const ushort4*)&featb[(size_t)s0 * FEAT + cb];
      accv.x = fmaf(a0, bfu2f(u0.x), accv.x); accv.y = fmaf(a0, bfu2f(u0.y), accv.y);
      accv.z = fmaf(a0, bfu2f(u0.z), accv.z); accv.w = fmaf(a0, bfu2f(u0.w), accv.w);
    }
  } else if (deg > 64) {
    // ---- generic register-only fallback (unreachable for Poisson(16)) ----
    const int h1 = lane & 3, j1 = lane >> 2;
    const float erd = er[n * HH + h1];
    float m = -INFINITY;
    for (int j = j1; j < deg; j += 16) {
      int s = csr_src[beg + j];
      float ev = el[s * HH + h1] + erd;
      ev = ev > 0.f ? ev : 0.2f * ev;
      m = fmaxf(m, ev);
    }
#pragma unroll
    for (int msk = 4; msk <= 32; msk <<= 1) m = fmaxf(m, __shfl_xor(m, msk));
    float ps = 0.f;
    for (int j = j1; j < deg; j += 16) {
      int s = csr_src[beg + j];
      float ev = el[s * HH + h1] + erd;
      ev = ev > 0.f ? ev : 0.2f * ev;
      ps += __expf(ev - m);
    }
#pragma unroll
    for (int msk = 4; msk <= 32; msk <<= 1) ps += __shfl_xor(ps, msk);
    const float m2 = __shfl(m, h2);
    const float psinv2 = 1.f / __shfl(ps, h2);
    const float erd2 = er[n * HH + h2];
    for (int j = 0; j < deg; ++j) {
      int s = csr_src[beg + j];
      float ev = el[s * HH + h2] + erd2;
      ev = ev > 0.f ? ev : 0.2f * ev;
      float a0 = __expf(ev - m2) * psinv2;
      ushort4 u0 = *(const ushort4*)&featb[(size_t)s * FEAT + cb];
      accv.x = fmaf(a0, bfu2f(u0.x), accv.x); accv.y = fmaf(a0, bfu2f(u0.y), accv.y);
      accv.z = fmaf(a0, bfu2f(u0.z), accv.z); accv.w = fmaf(a0, bfu2f(u0.w), accv.w);
    }
  }

  // ---- epilogue ----
  if (LAYER == 1) {
    float vv[4] = {accv.x, accv.y, accv.z, accv.w};
    short hi4[4], lo4[4];
#pragma unroll
    for (int c = 0; c < 4; ++c) {
      float v = vv[c];
      v = v > 0.f ? v : (__expf(v) - 1.f);  // ELU
      short hi = f2bf(v);
      hi4[c] = hi;
      lo4[c] = f2bf(v - bf2f(hi));
    }
    *(short4*)&outs[(size_t)n * 512 + cb] = make_short4(hi4[0], hi4[1], hi4[2], hi4[3]);
    *(short4*)&outs[(size_t)n * 512 + 256 + cb] = make_short4(lo4[0], lo4[1], lo4[2], lo4[3]);
  } else {
#pragma unroll
    for (int msk = 16; msk <= 32; msk <<= 1) {
      accv.x += __shfl_xor(accv.x, msk);
      accv.y += __shfl_xor(accv.y, msk);
      accv.z += __shfl_xor(accv.z, msk);
      accv.w += __shfl_xor(accv.w, msk);
    }
    if (lane < 16) {
      float4 o = make_float4(0.25f * accv.x, 0.25f * accv.y,
                             0.25f * accv.z, 0.25f * accv.w);
      *(float4*)&outp[(size_t)n * DD + (lane << 2)] = o;
    }
  }
}

extern "C" void kernel_launch(void* const* d_in, const int* in_sizes, int n_in,
                              void* d_out, int out_size, void* d_ws, size_t ws_size,
                              hipStream_t stream) {
  const float* x   = (const float*)d_in[0];
  const int*   src = (const int*)d_in[1];
  const int*   dst = (const int*)d_in[2];
  const float* W1  = (const float*)d_in[3];
  const float* al1 = (const float*)d_in[4];
  const float* ar1 = (const float*)d_in[5];
  const float* W2  = (const float*)d_in[6];
  const float* al2 = (const float*)d_in[7];
  const float* ar2 = (const float*)d_in[8];
  float* out = (float*)d_out;

  // workspace layout
  float* ws = (float*)d_ws;
  float* el = ws;                           // NNODES*HH
  float* er = el + NNODES * HH;             // NNODES*HH
  int* deg     = (int*)(er + NNODES * HH);  // NNODES
  int* off     = deg + NNODES;              // NNODES+1
  int* cursor  = off + NNODES + 1;          // NNODES
  int* bsum    = cursor + NNODES;           // 256
  int* csr_src = bsum + 256;                // NEDGES
  uintptr_t p = ((uintptr_t)(csr_src + NEDGES) + 63) & ~(uintptr_t)63;
  unsigned short* featb = (unsigned short*)p;      // NNODES*256 bf16 (25.6 MB)
  short* Apr  = (short*)(featb + (size_t)NNODES * 256);
  Apr = (short*)(((uintptr_t)Apr + 63) & ~(uintptr_t)63);  // MPAD*1024
  short* Bpr1 = Apr + (size_t)MPAD * 1024;  // 256*1024
  short* Bpr2 = Bpr1 + 256 * 1024;          // 256*512

  const int edgeBlocks = (NEDGES + 255) / 256;
  dim3 mfmaGrid(MPAD / 128, 2);

  // ---------- CSR build (shared by both layers) ----------
  hipMemsetAsync(deg, 0, NNODES * sizeof(int), stream);
  hist_kernel<<<edgeBlocks, 256, 0, stream>>>(dst, deg);
  scan_block_kernel<<<NB, 256, 0, stream>>>(deg, off, bsum);
  scan_top_kernel<<<1, 256, 0, stream>>>(bsum);
  scan_add_kernel<<<NB, 256, 0, stream>>>(off, bsum, cursor);
  scatter_kernel<<<edgeBlocks, 256, 0, stream>>>(src, dst, cursor, csr_src);

  // ---------- prep ----------
  split_a_kernel<<<MPAD / 2, 256, 0, stream>>>(x, Apr, NNODES);
  prep_b_kernel<<<768, 256, 0, stream>>>(W1, W2, Bpr1, Bpr2);

  // ---------- layer 1 : K=512 ----------
  mfma_gemm_kernel<<<mfmaGrid, 256, 0, stream>>>(Apr, Bpr1, featb, al1, ar1, el, er, NNODES, 512);
  gat_agg_kernel<1><<<NNODES / 4, 256, 0, stream>>>(off, csr_src, el, er, featb, nullptr, Apr);

  // ---------- layer 2 : K=256 ----------
  mfma_gemm_kernel<<<mfmaGrid, 256, 0, stream>>>(Apr, Bpr2, featb, al2, ar2, el, er, NNODES, 256);
  gat_agg_kernel<2><<<NNODES / 4, 256, 0, stream>>>(off, csr_src, el, er, featb, out, nullptr);
}

// Round 8
// 482.666 us; speedup vs baseline: 4.0962x; 1.1255x over previous
//
#include <hip/hip_runtime.h>

#define NNODES 50000
#define NEDGES 800000
#define HH 4
#define DD 64
#define FEAT 256   // HH*DD
#define NB ((NNODES + 255) / 256)
#define MPAD 50048 // 391 * 128

typedef __attribute__((ext_vector_type(8))) short frag_ab;   // 8 bf16
typedef __attribute__((ext_vector_type(4))) float frag_cd;   // 4 fp32

// ---------- bf16 helpers (RNE) ----------
__device__ __forceinline__ short f2bf(float v) {
  union { float f; unsigned u; } x; x.f = v;
  unsigned r = x.u + 0x7fffu + ((x.u >> 16) & 1u);
  return (short)(r >> 16);
}
__device__ __forceinline__ float bf2f(short b) {
  union { float f; unsigned u; } x;
  x.u = ((unsigned)(unsigned short)b) << 16;
  return x.f;
}
__device__ __forceinline__ float bfu2f(unsigned short b) {
  union { float f; unsigned u; } x;
  x.u = ((unsigned)b) << 16;
  return x.f;
}

// ---------- combined prep: A-split + both B-splits in one launch ----------
// blocks [0, MPAD/2): x [M,512] -> Ap [MPAD x 1024] = [Ahi|Alo]
// blocks [MPAD/2, +512): W1 -> Bp1 [256 x 1024]; next 256: W2 -> Bp2 [256 x 512]
__global__ __launch_bounds__(256) void prep_kernel(
    const float* __restrict__ x, const float* __restrict__ W1,
    const float* __restrict__ W2, short* __restrict__ Ap,
    short* __restrict__ Bp1, short* __restrict__ Bp2, int M) {
  int b = blockIdx.x;
  if (b < MPAD / 2) {
    int id = b * 256 + threadIdx.x;
    int m = id >> 7;
    int k4 = (id & 127) << 2;
    float4 v = make_float4(0.f, 0.f, 0.f, 0.f);
    if (m < M) v = *(const float4*)&x[(size_t)m * 512 + k4];
    short4 hi, lo;
    hi.x = f2bf(v.x); lo.x = f2bf(v.x - bf2f(hi.x));
    hi.y = f2bf(v.y); lo.y = f2bf(v.y - bf2f(hi.y));
    hi.z = f2bf(v.z); lo.z = f2bf(v.z - bf2f(hi.z));
    hi.w = f2bf(v.w); lo.w = f2bf(v.w - bf2f(hi.w));
    *(short4*)&Ap[(size_t)m * 1024 + k4] = hi;
    *(short4*)&Ap[(size_t)m * 1024 + 512 + k4] = lo;
  } else {
    int idx = (b - MPAD / 2) * 256 + threadIdx.x;
    const float* B; short* Bp; int K;
    if (idx < 512 * 256) { B = W1; Bp = Bp1; K = 512; }
    else { idx -= 512 * 256; B = W2; Bp = Bp2; K = 256; }
    int k = idx >> 8, n = idx & 255;
    float v = B[idx];
    short hi = f2bf(v);
    float lo = v - bf2f(hi);
    Bp[(size_t)n * 2 * K + k] = hi;
    Bp[(size_t)n * 2 * K + K + k] = f2bf(lo);
  }
}

// ---------- MFMA GEMM (BK=64, XOR-swizzled LDS) -> bf16 feat + fused el/er ----------
// Pass A: stage {A-hi, B-hi, B-lo}, acc += Ahi*Bhi + Ahi*Blo (64 MFMA/iter).
// Pass B: stage {A-lo, B-hi},      acc += Alo*Bhi          (32 MFMA/iter).
// LDS layout: [row][64 shorts]; slot s of row r holds global chunk s^(r&7)
// (chunk = 8 shorts = 16 B). Staging lane fetches chunk (lane&7)^(lane>>3),
// keeping global_load_lds's fixed lane-contiguous LDS dest conflict-free on read.
__global__ __launch_bounds__(256) void mfma_gemm_kernel(
    const short* __restrict__ Ap, const short* __restrict__ Bp,
    unsigned short* __restrict__ featb, const float* __restrict__ al,
    const float* __restrict__ ar, float* __restrict__ elp,
    float* __restrict__ erp, int M, int K) {
  __shared__ short As[128 * 64];   // 16 KB
  __shared__ short BsH[128 * 64];  // 16 KB
  __shared__ short BsL[128 * 64];  // 16 KB (pass A only)
  const int tid = threadIdx.x;
  const int w = tid >> 6, lane = tid & 63;
  const int q = lane >> 4, ln = lane & 15;
  const int rowBase = blockIdx.x * 128;
  const int colBase = blockIdx.y * 128;
  const int K2 = 2 * K;
  const int wm = (w >> 1) * 64;
  const int wn = (w & 1) * 64;

  frag_cd acc[4][4] = {};

  const int i1 = K >> 6;  // BK=64 iters per segment
  // staging roles: per instr j, lane covers row w*32+j*8+(lane>>3), chunk (lane&7)^(lane>>3)
  const int srow8 = lane >> 3;                 // 0..7
  const int scg = ((lane & 7) ^ srow8) * 8;    // swizzled global chunk offset (shorts)
  const int sw = ln & 7;                       // read-side swizzle key

  // ================= pass A: Ahi*(Bhi+Blo) =================
  for (int it = 0; it < i1; ++it) {
    const int kk = it << 6;
    __syncthreads();
#pragma unroll
    for (int j = 0; j < 4; ++j) {
      int rloc = w * 32 + j * 8 + srow8;
      __builtin_amdgcn_global_load_lds(
          (const __attribute__((address_space(1))) void*)(Ap + (size_t)(rowBase + rloc) * K2 + kk + scg),
          (__attribute__((address_space(3))) void*)(&As[(w * 32 + j * 8) * 64 + lane * 8]), 16, 0, 0);
    }
#pragma unroll
    for (int j = 0; j < 4; ++j) {
      int rloc = w * 32 + j * 8 + srow8;
      __builtin_amdgcn_global_load_lds(
          (const __attribute__((address_space(1))) void*)(Bp + (size_t)(colBase + rloc) * K2 + kk + scg),
          (__attribute__((address_space(3))) void*)(&BsH[(w * 32 + j * 8) * 64 + lane * 8]), 16, 0, 0);
    }
#pragma unroll
    for (int j = 0; j < 4; ++j) {
      int rloc = w * 32 + j * 8 + srow8;
      __builtin_amdgcn_global_load_lds(
          (const __attribute__((address_space(1))) void*)(Bp + (size_t)(colBase + rloc) * K2 + K + kk + scg),
          (__attribute__((address_space(3))) void*)(&BsL[(w * 32 + j * 8) * 64 + lane * 8]), 16, 0, 0);
    }
    __syncthreads();

#pragma unroll
    for (int ksub = 0; ksub < 2; ++ksub) {
      const int slot = ((ksub * 4 + q) ^ sw) * 8;
      frag_ab a[4], bh[4], bl[4];
#pragma unroll
      for (int i = 0; i < 4; ++i)
        a[i] = *(const frag_ab*)&As[(wm + i * 16 + ln) * 64 + slot];
#pragma unroll
      for (int j = 0; j < 4; ++j) {
        bh[j] = *(const frag_ab*)&BsH[(wn + j * 16 + ln) * 64 + slot];
        bl[j] = *(const frag_ab*)&BsL[(wn + j * 16 + ln) * 64 + slot];
      }
#pragma unroll
      for (int i = 0; i < 4; ++i)
#pragma unroll
        for (int j = 0; j < 4; ++j)
          acc[i][j] = __builtin_amdgcn_mfma_f32_16x16x32_bf16(a[i], bh[j], acc[i][j], 0, 0, 0);
#pragma unroll
      for (int i = 0; i < 4; ++i)
#pragma unroll
        for (int j = 0; j < 4; ++j)
          acc[i][j] = __builtin_amdgcn_mfma_f32_16x16x32_bf16(a[i], bl[j], acc[i][j], 0, 0, 0);
    }
  }

  // ================= pass B: Alo*Bhi =================
  for (int it = 0; it < i1; ++it) {
    const int kk = it << 6;
    __syncthreads();
#pragma unroll
    for (int j = 0; j < 4; ++j) {
      int rloc = w * 32 + j * 8 + srow8;
      __builtin_amdgcn_global_load_lds(
          (const __attribute__((address_space(1))) void*)(Ap + (size_t)(rowBase + rloc) * K2 + K + kk + scg),
          (__attribute__((address_space(3))) void*)(&As[(w * 32 + j * 8) * 64 + lane * 8]), 16, 0, 0);
    }
#pragma unroll
    for (int j = 0; j < 4; ++j) {
      int rloc = w * 32 + j * 8 + srow8;
      __builtin_amdgcn_global_load_lds(
          (const __attribute__((address_space(1))) void*)(Bp + (size_t)(colBase + rloc) * K2 + kk + scg),
          (__attribute__((address_space(3))) void*)(&BsH[(w * 32 + j * 8) * 64 + lane * 8]), 16, 0, 0);
    }
    __syncthreads();

#pragma unroll
    for (int ksub = 0; ksub < 2; ++ksub) {
      const int slot = ((ksub * 4 + q) ^ sw) * 8;
      frag_ab a[4], bh[4];
#pragma unroll
      for (int i = 0; i < 4; ++i)
        a[i] = *(const frag_ab*)&As[(wm + i * 16 + ln) * 64 + slot];
#pragma unroll
      for (int j = 0; j < 4; ++j)
        bh[j] = *(const frag_ab*)&BsH[(wn + j * 16 + ln) * 64 + slot];
#pragma unroll
      for (int i = 0; i < 4; ++i)
#pragma unroll
        for (int j = 0; j < 4; ++j)
          acc[i][j] = __builtin_amdgcn_mfma_f32_16x16x32_bf16(a[i], bh[j], acc[i][j], 0, 0, 0);
    }
  }

  // ---- bf16 feat store (D row = q*4+reg, col = ln) ----
#pragma unroll
  for (int i = 0; i < 4; ++i) {
    int rowg = rowBase + wm + i * 16 + q * 4;
#pragma unroll
    for (int r = 0; r < 4; ++r) {
      int row = rowg + r;
      if (row < M) {
#pragma unroll
        for (int j = 0; j < 4; ++j) {
          int col = colBase + wn + j * 16 + ln;
          featb[(size_t)row * 256 + col] = (unsigned short)f2bf(acc[i][j][r]);
        }
      }
    }
  }

  // ---- fused el/er: this wave's 64 cols == one head (exact fp32) ----
  const int h = (colBase + wn) >> 6;
  float alv[4], arv[4];
#pragma unroll
  for (int j = 0; j < 4; ++j) {
    alv[j] = al[h * DD + j * 16 + ln];
    arv[j] = ar[h * DD + j * 16 + ln];
  }
#pragma unroll
  for (int i = 0; i < 4; ++i) {
#pragma unroll
    for (int r = 0; r < 4; ++r) {
      float pl = 0.f, pr = 0.f;
#pragma unroll
      for (int j = 0; j < 4; ++j) {
        pl = fmaf(acc[i][j][r], alv[j], pl);
        pr = fmaf(acc[i][j][r], arv[j], pr);
      }
#pragma unroll
      for (int msk = 1; msk < 16; msk <<= 1) {
        pl += __shfl_xor(pl, msk);
        pr += __shfl_xor(pr, msk);
      }
      int row = rowBase + wm + i * 16 + q * 4 + r;
      if (ln == 0 && row < M) {
        elp[row * HH + h] = pl;
        erp[row * HH + h] = pr;
      }
    }
  }
}

// ---------- CSR build ----------
__global__ __launch_bounds__(256) void hist_kernel(const int* __restrict__ dst,
                                                   int* __restrict__ deg) {
  int e = blockIdx.x * 256 + threadIdx.x;
  if (e < NEDGES) atomicAdd(&deg[dst[e]], 1);
}

__global__ __launch_bounds__(256) void scan_block_kernel(const int* __restrict__ deg,
                                                         int* __restrict__ off,
                                                         int* __restrict__ bsum) {
  __shared__ int tmp[256];
  int b = blockIdx.x, t = threadIdx.x;
  int i = b * 256 + t;
  int v = (i < NNODES) ? deg[i] : 0;
  tmp[t] = v;
  __syncthreads();
  for (int s = 1; s < 256; s <<= 1) {
    int add = (t >= s) ? tmp[t - s] : 0;
    __syncthreads();
    tmp[t] += add;
    __syncthreads();
  }
  if (i < NNODES) off[i + 1] = tmp[t];
  if (t == 255) bsum[b] = tmp[255];
}

__global__ __launch_bounds__(256) void scan_top_kernel(int* __restrict__ bsum) {
  __shared__ int tmp[256];
  int t = threadIdx.x;
  int v = (t < NB) ? bsum[t] : 0;
  tmp[t] = v;
  __syncthreads();
  for (int s = 1; s < 256; s <<= 1) {
    int add = (t >= s) ? tmp[t - s] : 0;
    __syncthreads();
    tmp[t] += add;
    __syncthreads();
  }
  if (t < NB) bsum[t] = tmp[t] - v;
}

__global__ __launch_bounds__(256) void scan_add_kernel(int* __restrict__ off,
                                                       const int* __restrict__ bsum,
                                                       int* __restrict__ cursor) {
  int b = blockIdx.x, t = threadIdx.x;
  int i = b * 256 + t;
  if (i < NNODES) {
    int val = off[i + 1] + bsum[b];
    off[i + 1] = val;
    if (i + 1 < NNODES) cursor[i + 1] = val;
  }
  if (i == 0) { off[0] = 0; cursor[0] = 0; }
}

__global__ __launch_bounds__(256) void scatter_kernel(const int* __restrict__ src,
                                                      const int* __restrict__ dst,
                                                      int* __restrict__ cursor,
                                                      int* __restrict__ csr_src) {
  int e = blockIdx.x * 256 + threadIdx.x;
  if (e >= NEDGES) return;
  int d = dst[e];
  int pos = atomicAdd(&cursor[d], 1);
  csr_src[pos] = src[e];
}

// ---------- fused per-dst-node GAT: one WAVE per node, bf16 gather ----------
template <int LAYER>
__global__ __launch_bounds__(256) void gat_agg_kernel(
    const int* __restrict__ off, const int* __restrict__ csr_src,
    const float* __restrict__ el, const float* __restrict__ er,
    const unsigned short* __restrict__ featb, float* __restrict__ outp,
    short* __restrict__ outs) {
  __shared__ float sA[4][HH][68];  // [wave][head][edge] normalized weights
  __shared__ int sS[4][64];        // [wave][edge] src ids
  const int w = threadIdx.x >> 6;
  const int lane = threadIdx.x & 63;
  const int n = blockIdx.x * 4 + w;   // NNODES = 4 * 12500 exactly
  const int beg = off[n];
  const int deg = off[n + 1] - beg;

  float4 accv = make_float4(0.f, 0.f, 0.f, 0.f);
  const int h2 = lane >> 4;
  const int cb = lane << 2;

  if (deg > 0 && deg <= 64) {
    // ---- phase 1: scores once per (edge,head), shfl reductions ----
    const int h1 = lane & 3, j1 = lane >> 2;
    const float erd = er[n * HH + h1];
    float e[4], a[4];
    float m = -INFINITY;
#pragma unroll
    for (int p = 0; p < 4; ++p) {
      int j = j1 + p * 16;
      float ev = -INFINITY;
      if (j < deg) {
        int s = csr_src[beg + j];
        if (h1 == 0) sS[w][j] = s;
        ev = el[s * HH + h1] + erd;
        ev = ev > 0.f ? ev : 0.2f * ev;
      }
      e[p] = ev;
      m = fmaxf(m, ev);
    }
#pragma unroll
    for (int msk = 4; msk <= 32; msk <<= 1) m = fmaxf(m, __shfl_xor(m, msk));
    float ps = 0.f;
#pragma unroll
    for (int p = 0; p < 4; ++p) {
      a[p] = (j1 + p * 16 < deg) ? __expf(e[p] - m) : 0.f;
      ps += a[p];
    }
#pragma unroll
    for (int msk = 4; msk <= 32; msk <<= 1) ps += __shfl_xor(ps, msk);
    const float sinv = 1.f / ps;
#pragma unroll
    for (int p = 0; p < 4; ++p) {
      int j = j1 + p * 16;
      if (j < deg) sA[w][h1][j] = a[p] * sinv;
    }

    // ---- phase 2: bf16 gather (512 B/wave per edge), unrolled x4 ----
    int j = 0;
    for (; j + 4 <= deg; j += 4) {
      int s0 = sS[w][j], s1 = sS[w][j + 1], s2 = sS[w][j + 2], s3 = sS[w][j + 3];
      float a0 = sA[w][h2][j], a1 = sA[w][h2][j + 1];
      float a2 = sA[w][h2][j + 2], a3 = sA[w][h2][j + 3];
      ushort4 u0 = *(const ushort4*)&featb[(size_t)s0 * FEAT + cb];
      ushort4 u1 = *(const ushort4*)&featb[(size_t)s1 * FEAT + cb];
      ushort4 u2 = *(const ushort4*)&featb[(size_t)s2 * FEAT + cb];
      ushort4 u3 = *(const ushort4*)&featb[(size_t)s3 * FEAT + cb];
      accv.x = fmaf(a0, bfu2f(u0.x), accv.x); accv.y = fmaf(a0, bfu2f(u0.y), accv.y);
      accv.z = fmaf(a0, bfu2f(u0.z), accv.z); accv.w = fmaf(a0, bfu2f(u0.w), accv.w);
      accv.x = fmaf(a1, bfu2f(u1.x), accv.x); accv.y = fmaf(a1, bfu2f(u1.y), accv.y);
      accv.z = fmaf(a1, bfu2f(u1.z), accv.z); accv.w = fmaf(a1, bfu2f(u1.w), accv.w);
      accv.x = fmaf(a2, bfu2f(u2.x), accv.x); accv.y = fmaf(a2, bfu2f(u2.y), accv.y);
      accv.z = fmaf(a2, bfu2f(u2.z), accv.z); accv.w = fmaf(a2, bfu2f(u2.w), accv.w);
      accv.x = fmaf(a3, bfu2f(u3.x), accv.x); accv.y = fmaf(a3, bfu2f(u3.y), accv.y);
      accv.z = fmaf(a3, bfu2f(u3.z), accv.z); accv.w = fmaf(a3, bfu2f(u3.w), accv.w);
    }
    for (; j < deg; ++j) {
      int s0 = sS[w][j];
      float a0 = sA[w][h2][j];
      ushort4 u0 = *(const ushort4*)&featb[(size_t)s0 * FEAT + cb];
      accv.x = fmaf(a0, bfu2f(u0.x), accv.x); accv.y = fmaf(a0, bfu2f(u0.y), accv.y);
      accv.z = fmaf(a0, bfu2f(u0.z), accv.z); accv.w = fmaf(a0, bfu2f(u0.w), accv.w);
    }
  } else if (deg > 64) {
    // ---- generic register-only fallback (unreachable for Poisson(16)) ----
    const int h1 = lane & 3, j1 = lane >> 2;
    const float erd = er[n * HH + h1];
    float m = -INFINITY;
    for (int j = j1; j < deg; j += 16) {
      int s = csr_src[beg + j];
      float ev = el[s * HH + h1] + erd;
      ev = ev > 0.f ? ev : 0.2f * ev;
      m = fmaxf(m, ev);
    }
#pragma unroll
    for (int msk = 4; msk <= 32; msk <<= 1) m = fmaxf(m, __shfl_xor(m, msk));
    float ps = 0.f;
    for (int j = j1; j < deg; j += 16) {
      int s = csr_src[beg + j];
      float ev = el[s * HH + h1] + erd;
      ev = ev > 0.f ? ev : 0.2f * ev;
      ps += __expf(ev - m);
    }
#pragma unroll
    for (int msk = 4; msk <= 32; msk <<= 1) ps += __shfl_xor(ps, msk);
    const float m2 = __shfl(m, h2);
    const float psinv2 = 1.f / __shfl(ps, h2);
    const float erd2 = er[n * HH + h2];
    for (int j = 0; j < deg; ++j) {
      int s = csr_src[beg + j];
      float ev = el[s * HH + h2] + erd2;
      ev = ev > 0.f ? ev : 0.2f * ev;
      float a0 = __expf(ev - m2) * psinv2;
      ushort4 u0 = *(const ushort4*)&featb[(size_t)s * FEAT + cb];
      accv.x = fmaf(a0, bfu2f(u0.x), accv.x); accv.y = fmaf(a0, bfu2f(u0.y), accv.y);
      accv.z = fmaf(a0, bfu2f(u0.z), accv.z); accv.w = fmaf(a0, bfu2f(u0.w), accv.w);
    }
  }

  // ---- epilogue ----
  if (LAYER == 1) {
    float vv[4] = {accv.x, accv.y, accv.z, accv.w};
    short hi4[4], lo4[4];
#pragma unroll
    for (int c = 0; c < 4; ++c) {
      float v = vv[c];
      v = v > 0.f ? v : (__expf(v) - 1.f);  // ELU
      short hi = f2bf(v);
      hi4[c] = hi;
      lo4[c] = f2bf(v - bf2f(hi));
    }
    *(short4*)&outs[(size_t)n * 512 + cb] = make_short4(hi4[0], hi4[1], hi4[2], hi4[3]);
    *(short4*)&outs[(size_t)n * 512 + 256 + cb] = make_short4(lo4[0], lo4[1], lo4[2], lo4[3]);
  } else {
#pragma unroll
    for (int msk = 16; msk <= 32; msk <<= 1) {
      accv.x += __shfl_xor(accv.x, msk);
      accv.y += __shfl_xor(accv.y, msk);
      accv.z += __shfl_xor(accv.z, msk);
      accv.w += __shfl_xor(accv.w, msk);
    }
    if (lane < 16) {
      float4 o = make_float4(0.25f * accv.x, 0.25f * accv.y,
                             0.25f * accv.z, 0.25f * accv.w);
      *(float4*)&outp[(size_t)n * DD + (lane << 2)] = o;
    }
  }
}

extern "C" void kernel_launch(void* const* d_in, const int* in_sizes, int n_in,
                              void* d_out, int out_size, void* d_ws, size_t ws_size,
                              hipStream_t stream) {
  const float* x   = (const float*)d_in[0];
  const int*   src = (const int*)d_in[1];
  const int*   dst = (const int*)d_in[2];
  const float* W1  = (const float*)d_in[3];
  const float* al1 = (const float*)d_in[4];
  const float* ar1 = (const float*)d_in[5];
  const float* W2  = (const float*)d_in[6];
  const float* al2 = (const float*)d_in[7];
  const float* ar2 = (const float*)d_in[8];
  float* out = (float*)d_out;

  // workspace layout
  float* ws = (float*)d_ws;
  float* el = ws;                           // NNODES*HH
  float* er = el + NNODES * HH;             // NNODES*HH
  int* deg     = (int*)(er + NNODES * HH);  // NNODES
  int* off     = deg + NNODES;              // NNODES+1
  int* cursor  = off + NNODES + 1;          // NNODES
  int* bsum    = cursor + NNODES;           // 256
  int* csr_src = bsum + 256;                // NEDGES
  uintptr_t p = ((uintptr_t)(csr_src + NEDGES) + 63) & ~(uintptr_t)63;
  unsigned short* featb = (unsigned short*)p;      // NNODES*256 bf16 (25.6 MB)
  short* Apr  = (short*)(featb + (size_t)NNODES * 256);
  Apr = (short*)(((uintptr_t)Apr + 63) & ~(uintptr_t)63);  // MPAD*1024
  short* Bpr1 = Apr + (size_t)MPAD * 1024;  // 256*1024
  short* Bpr2 = Bpr1 + 256 * 1024;          // 256*512

  const int edgeBlocks = (NEDGES + 255) / 256;
  dim3 mfmaGrid(MPAD / 128, 2);

  // ---------- CSR build (shared by both layers) ----------
  hipMemsetAsync(deg, 0, NNODES * sizeof(int), stream);
  hist_kernel<<<edgeBlocks, 256, 0, stream>>>(dst, deg);
  scan_block_kernel<<<NB, 256, 0, stream>>>(deg, off, bsum);
  scan_top_kernel<<<1, 256, 0, stream>>>(bsum);
  scan_add_kernel<<<NB, 256, 0, stream>>>(off, bsum, cursor);
  scatter_kernel<<<edgeBlocks, 256, 0, stream>>>(src, dst, cursor, csr_src);

  // ---------- prep (A-split + both B-splits, one launch) ----------
  prep_kernel<<<MPAD / 2 + 768, 256, 0, stream>>>(x, W1, W2, Apr, Bpr1, Bpr2, NNODES);

  // ---------- layer 1 : K=512 ----------
  mfma_gemm_kernel<<<mfmaGrid, 256, 0, stream>>>(Apr, Bpr1, featb, al1, ar1, el, er, NNODES, 512);
  gat_agg_kernel<1><<<NNODES / 4, 256, 0, stream>>>(off, csr_src, el, er, featb, nullptr, Apr);

  // ---------- layer 2 : K=256 ----------
  mfma_gemm_kernel<<<mfmaGrid, 256, 0, stream>>>(Apr, Bpr2, featb, al2, ar2, el, er, NNODES, 256);
  gat_agg_kernel<2><<<NNODES / 4, 256, 0, stream>>>(off, csr_src, el, er, featb, out, nullptr);
}

// Round 9
// 439.556 us; speedup vs baseline: 4.4979x; 1.0981x over previous
//
#include <hip/hip_runtime.h>

#define NNODES 50000
#define NEDGES 800000
#define HH 4
#define DD 64
#define FEAT 256   // HH*DD
#define NB ((NNODES + 255) / 256)
#define MPAD 50048 // 391 * 128

typedef __attribute__((ext_vector_type(8))) _Float16 frag16;  // 8 f16 (4 VGPRs)
typedef __attribute__((ext_vector_type(4))) float frag_cd;    // 4 fp32
typedef __attribute__((ext_vector_type(4))) _Float16 h4v;     // 8-byte f16 vector

// ---------- combined prep: x->fp16 A' + both W->fp16 B'^T in one launch ----------
__global__ __launch_bounds__(256) void prep_kernel(
    const float* __restrict__ x, const float* __restrict__ W1,
    const float* __restrict__ W2, _Float16* __restrict__ Ap,
    _Float16* __restrict__ Bp1, _Float16* __restrict__ Bp2, int M) {
  int b = blockIdx.x;
  if (b < MPAD / 2) {
    int id = b * 256 + threadIdx.x;       // MPAD*128 quads
    int m = id >> 7;
    int k4 = (id & 127) << 2;
    float4 v = make_float4(0.f, 0.f, 0.f, 0.f);
    if (m < M) v = *(const float4*)&x[(size_t)m * 512 + k4];
    h4v o;
    o[0] = (_Float16)v.x; o[1] = (_Float16)v.y;
    o[2] = (_Float16)v.z; o[3] = (_Float16)v.w;
    *(h4v*)&Ap[(size_t)m * 512 + k4] = o;
  } else {
    int idx = (b - MPAD / 2) * 256 + threadIdx.x;  // (512+256)*256 elems
    if (idx < 512 * 256) {
      int k = idx >> 8, n = idx & 255;
      Bp1[(size_t)n * 512 + k] = (_Float16)W1[idx];
    } else {
      idx -= 512 * 256;
      int k = idx >> 8, n = idx & 255;
      Bp2[(size_t)n * 256 + k] = (_Float16)W2[idx];
    }
  }
}

// ---------- single-product fp16 MFMA GEMM (BK=64, XOR-swizzled LDS) ----------
// featb[M,256] f16 = A@B (A' [MPAD x K] f16, B'^T [256 x K] f16);
// el/er from exact fp32 accumulators, fused.
// LDS: slot s of row r holds global chunk s^(r&7) (chunk = 8 f16 = 16 B);
// staging lane fetches chunk (lane&7)^(lane>>3) -> conflict-free both sides.
__global__ __launch_bounds__(256) void mfma_gemm_kernel(
    const _Float16* __restrict__ Ap, const _Float16* __restrict__ Bp,
    _Float16* __restrict__ featb, const float* __restrict__ al,
    const float* __restrict__ ar, float* __restrict__ elp,
    float* __restrict__ erp, int M, int K) {
  __shared__ _Float16 As[128 * 64];  // 16 KB
  __shared__ _Float16 Bs[128 * 64];  // 16 KB
  const int tid = threadIdx.x;
  const int w = tid >> 6, lane = tid & 63;
  const int q = lane >> 4, ln = lane & 15;
  const int rowBase = blockIdx.x * 128;
  const int colBase = blockIdx.y * 128;
  const int wm = (w >> 1) * 64;
  const int wn = (w & 1) * 64;

  frag_cd acc[4][4] = {};

  const int i1 = K >> 6;  // BK=64
  const int srow8 = lane >> 3;               // 0..7
  const int scg = ((lane & 7) ^ srow8) * 8;  // swizzled global chunk (f16 units)
  const int sw = ln & 7;                     // read-side swizzle key

  for (int it = 0; it < i1; ++it) {
    const int kk = it << 6;
    __syncthreads();
#pragma unroll
    for (int j = 0; j < 4; ++j) {
      int rloc = w * 32 + j * 8 + srow8;
      __builtin_amdgcn_global_load_lds(
          (const __attribute__((address_space(1))) void*)(Ap + (size_t)(rowBase + rloc) * K + kk + scg),
          (__attribute__((address_space(3))) void*)(&As[(w * 32 + j * 8) * 64 + lane * 8]), 16, 0, 0);
    }
#pragma unroll
    for (int j = 0; j < 4; ++j) {
      int rloc = w * 32 + j * 8 + srow8;
      __builtin_amdgcn_global_load_lds(
          (const __attribute__((address_space(1))) void*)(Bp + (size_t)(colBase + rloc) * K + kk + scg),
          (__attribute__((address_space(3))) void*)(&Bs[(w * 32 + j * 8) * 64 + lane * 8]), 16, 0, 0);
    }
    __syncthreads();

#pragma unroll
    for (int ksub = 0; ksub < 2; ++ksub) {
      const int slot = ((ksub * 4 + q) ^ sw) * 8;
      frag16 a[4], b[4];
#pragma unroll
      for (int i = 0; i < 4; ++i)
        a[i] = *(const frag16*)&As[(wm + i * 16 + ln) * 64 + slot];
#pragma unroll
      for (int j = 0; j < 4; ++j)
        b[j] = *(const frag16*)&Bs[(wn + j * 16 + ln) * 64 + slot];
#pragma unroll
      for (int i = 0; i < 4; ++i)
#pragma unroll
        for (int j = 0; j < 4; ++j)
          acc[i][j] = __builtin_amdgcn_mfma_f32_16x16x32_f16(a[i], b[j], acc[i][j], 0, 0, 0);
    }
  }

  // ---- f16 feat store (D row = q*4+reg, col = ln) ----
#pragma unroll
  for (int i = 0; i < 4; ++i) {
    int rowg = rowBase + wm + i * 16 + q * 4;
#pragma unroll
    for (int r = 0; r < 4; ++r) {
      int row = rowg + r;
      if (row < M) {
#pragma unroll
        for (int j = 0; j < 4; ++j) {
          int col = colBase + wn + j * 16 + ln;
          featb[(size_t)row * 256 + col] = (_Float16)acc[i][j][r];
        }
      }
    }
  }

  // ---- fused el/er: this wave's 64 cols == one head (exact fp32) ----
  const int h = (colBase + wn) >> 6;
  float alv[4], arv[4];
#pragma unroll
  for (int j = 0; j < 4; ++j) {
    alv[j] = al[h * DD + j * 16 + ln];
    arv[j] = ar[h * DD + j * 16 + ln];
  }
#pragma unroll
  for (int i = 0; i < 4; ++i) {
#pragma unroll
    for (int r = 0; r < 4; ++r) {
      float pl = 0.f, pr = 0.f;
#pragma unroll
      for (int j = 0; j < 4; ++j) {
        pl = fmaf(acc[i][j][r], alv[j], pl);
        pr = fmaf(acc[i][j][r], arv[j], pr);
      }
#pragma unroll
      for (int msk = 1; msk < 16; msk <<= 1) {
        pl += __shfl_xor(pl, msk);
        pr += __shfl_xor(pr, msk);
      }
      int row = rowBase + wm + i * 16 + q * 4 + r;
      if (ln == 0 && row < M) {
        elp[row * HH + h] = pl;
        erp[row * HH + h] = pr;
      }
    }
  }
}

// ---------- CSR build ----------
__global__ __launch_bounds__(256) void hist_kernel(const int* __restrict__ dst,
                                                   int* __restrict__ deg) {
  int e = blockIdx.x * 256 + threadIdx.x;
  if (e < NEDGES) atomicAdd(&deg[dst[e]], 1);
}

__global__ __launch_bounds__(256) void scan_block_kernel(const int* __restrict__ deg,
                                                         int* __restrict__ off,
                                                         int* __restrict__ bsum) {
  __shared__ int tmp[256];
  int b = blockIdx.x, t = threadIdx.x;
  int i = b * 256 + t;
  int v = (i < NNODES) ? deg[i] : 0;
  tmp[t] = v;
  __syncthreads();
  for (int s = 1; s < 256; s <<= 1) {
    int add = (t >= s) ? tmp[t - s] : 0;
    __syncthreads();
    tmp[t] += add;
    __syncthreads();
  }
  if (i < NNODES) off[i + 1] = tmp[t];
  if (t == 255) bsum[b] = tmp[255];
}

__global__ __launch_bounds__(256) void scan_top_kernel(int* __restrict__ bsum) {
  __shared__ int tmp[256];
  int t = threadIdx.x;
  int v = (t < NB) ? bsum[t] : 0;
  tmp[t] = v;
  __syncthreads();
  for (int s = 1; s < 256; s <<= 1) {
    int add = (t >= s) ? tmp[t - s] : 0;
    __syncthreads();
    tmp[t] += add;
    __syncthreads();
  }
  if (t < NB) bsum[t] = tmp[t] - v;
}

__global__ __launch_bounds__(256) void scan_add_kernel(int* __restrict__ off,
                                                       const int* __restrict__ bsum,
                                                       int* __restrict__ cursor) {
  int b = blockIdx.x, t = threadIdx.x;
  int i = b * 256 + t;
  if (i < NNODES) {
    int val = off[i + 1] + bsum[b];
    off[i + 1] = val;
    if (i + 1 < NNODES) cursor[i + 1] = val;
  }
  if (i == 0) { off[0] = 0; cursor[0] = 0; }
}

__global__ __launch_bounds__(256) void scatter_kernel(const int* __restrict__ src,
                                                      const int* __restrict__ dst,
                                                      int* __restrict__ cursor,
                                                      int* __restrict__ csr_src) {
  int e = blockIdx.x * 256 + threadIdx.x;
  if (e >= NEDGES) return;
  int d = dst[e];
  int pos = atomicAdd(&cursor[d], 1);
  csr_src[pos] = src[e];
}

// ---------- fused per-dst-node GAT: one WAVE per node, f16 gather ----------
template <int LAYER>
__global__ __launch_bounds__(256) void gat_agg_kernel(
    const int* __restrict__ off, const int* __restrict__ csr_src,
    const float* __restrict__ el, const float* __restrict__ er,
    const _Float16* __restrict__ featb, float* __restrict__ outp,
    _Float16* __restrict__ outs) {
  __shared__ float sA[4][HH][68];  // [wave][head][edge] normalized weights
  __shared__ int sS[4][64];        // [wave][edge] src ids
  const int w = threadIdx.x >> 6;
  const int lane = threadIdx.x & 63;
  const int n = blockIdx.x * 4 + w;   // NNODES = 4 * 12500 exactly
  const int beg = off[n];
  const int deg = off[n + 1] - beg;

  float4 accv = make_float4(0.f, 0.f, 0.f, 0.f);
  const int h2 = lane >> 4;
  const int cb = lane << 2;

  if (deg > 0 && deg <= 64) {
    // ---- phase 1: scores once per (edge,head), shfl reductions ----
    const int h1 = lane & 3, j1 = lane >> 2;
    const float erd = er[n * HH + h1];
    float e[4], a[4];
    float m = -INFINITY;
#pragma unroll
    for (int p = 0; p < 4; ++p) {
      int j = j1 + p * 16;
      float ev = -INFINITY;
      if (j < deg) {
        int s = csr_src[beg + j];
        if (h1 == 0) sS[w][j] = s;
        ev = el[s * HH + h1] + erd;
        ev = ev > 0.f ? ev : 0.2f * ev;
      }
      e[p] = ev;
      m = fmaxf(m, ev);
    }
#pragma unroll
    for (int msk = 4; msk <= 32; msk <<= 1) m = fmaxf(m, __shfl_xor(m, msk));
    float ps = 0.f;
#pragma unroll
    for (int p = 0; p < 4; ++p) {
      a[p] = (j1 + p * 16 < deg) ? __expf(e[p] - m) : 0.f;
      ps += a[p];
    }
#pragma unroll
    for (int msk = 4; msk <= 32; msk <<= 1) ps += __shfl_xor(ps, msk);
    const float sinv = 1.f / ps;
#pragma unroll
    for (int p = 0; p < 4; ++p) {
      int j = j1 + p * 16;
      if (j < deg) sA[w][h1][j] = a[p] * sinv;
    }

    // ---- phase 2: f16 gather (512 B/wave per edge), unrolled x4 ----
    int j = 0;
    for (; j + 4 <= deg; j += 4) {
      int s0 = sS[w][j], s1 = sS[w][j + 1], s2 = sS[w][j + 2], s3 = sS[w][j + 3];
      float a0 = sA[w][h2][j], a1 = sA[w][h2][j + 1];
      float a2 = sA[w][h2][j + 2], a3 = sA[w][h2][j + 3];
      h4v u0 = *(const h4v*)&featb[(size_t)s0 * FEAT + cb];
      h4v u1 = *(const h4v*)&featb[(size_t)s1 * FEAT + cb];
      h4v u2 = *(const h4v*)&featb[(size_t)s2 * FEAT + cb];
      h4v u3 = *(const h4v*)&featb[(size_t)s3 * FEAT + cb];
      accv.x = fmaf(a0, (float)u0[0], accv.x); accv.y = fmaf(a0, (float)u0[1], accv.y);
      accv.z = fmaf(a0, (float)u0[2], accv.z); accv.w = fmaf(a0, (float)u0[3], accv.w);
      accv.x = fmaf(a1, (float)u1[0], accv.x); accv.y = fmaf(a1, (float)u1[1], accv.y);
      accv.z = fmaf(a1, (float)u1[2], accv.z); accv.w = fmaf(a1, (float)u1[3], accv.w);
      accv.x = fmaf(a2, (float)u2[0], accv.x); accv.y = fmaf(a2, (float)u2[1], accv.y);
      accv.z = fmaf(a2, (float)u2[2], accv.z); accv.w = fmaf(a2, (float)u2[3], accv.w);
      accv.x = fmaf(a3, (float)u3[0], accv.x); accv.y = fmaf(a3, (float)u3[1], accv.y);
      accv.z = fmaf(a3, (float)u3[2], accv.z); accv.w = fmaf(a3, (float)u3[3], accv.w);
    }
    for (; j < deg; ++j) {
      int s0 = sS[w][j];
      float a0 = sA[w][h2][j];
      h4v u0 = *(const h4v*)&featb[(size_t)s0 * FEAT + cb];
      accv.x = fmaf(a0, (float)u0[0], accv.x); accv.y = fmaf(a0, (float)u0[1], accv.y);
      accv.z = fmaf(a0, (float)u0[2], accv.z); accv.w = fmaf(a0, (float)u0[3], accv.w);
    }
  } else if (deg > 64) {
    // ---- generic register-only fallback (unreachable for Poisson(16)) ----
    const int h1 = lane & 3, j1 = lane >> 2;
    const float erd = er[n * HH + h1];
    float m = -INFINITY;
    for (int j = j1; j < deg; j += 16) {
      int s = csr_src[beg + j];
      float ev = el[s * HH + h1] + erd;
      ev = ev > 0.f ? ev : 0.2f * ev;
      m = fmaxf(m, ev);
    }
#pragma unroll
    for (int msk = 4; msk <= 32; msk <<= 1) m = fmaxf(m, __shfl_xor(m, msk));
    float ps = 0.f;
    for (int j = j1; j < deg; j += 16) {
      int s = csr_src[beg + j];
      float ev = el[s * HH + h1] + erd;
      ev = ev > 0.f ? ev : 0.2f * ev;
      ps += __expf(ev - m);
    }
#pragma unroll
    for (int msk = 4; msk <= 32; msk <<= 1) ps += __shfl_xor(ps, msk);
    const float m2 = __shfl(m, h2);
    const float psinv2 = 1.f / __shfl(ps, h2);
    const float erd2 = er[n * HH + h2];
    for (int j = 0; j < deg; ++j) {
      int s = csr_src[beg + j];
      float ev = el[s * HH + h2] + erd2;
      ev = ev > 0.f ? ev : 0.2f * ev;
      float a0 = __expf(ev - m2) * psinv2;
      h4v u0 = *(const h4v*)&featb[(size_t)s * FEAT + cb];
      accv.x = fmaf(a0, (float)u0[0], accv.x); accv.y = fmaf(a0, (float)u0[1], accv.y);
      accv.z = fmaf(a0, (float)u0[2], accv.z); accv.w = fmaf(a0, (float)u0[3], accv.w);
    }
  }

  // ---- epilogue ----
  if (LAYER == 1) {
    float vv[4] = {accv.x, accv.y, accv.z, accv.w};
    h4v o;
#pragma unroll
    for (int c = 0; c < 4; ++c) {
      float v = vv[c];
      v = v > 0.f ? v : (__expf(v) - 1.f);  // ELU
      o[c] = (_Float16)v;
    }
    *(h4v*)&outs[(size_t)n * 256 + cb] = o;  // next layer's A' row (f16)
  } else {
#pragma unroll
    for (int msk = 16; msk <= 32; msk <<= 1) {
      accv.x += __shfl_xor(accv.x, msk);
      accv.y += __shfl_xor(accv.y, msk);
      accv.z += __shfl_xor(accv.z, msk);
      accv.w += __shfl_xor(accv.w, msk);
    }
    if (lane < 16) {
      float4 o = make_float4(0.25f * accv.x, 0.25f * accv.y,
                             0.25f * accv.z, 0.25f * accv.w);
      *(float4*)&outp[(size_t)n * DD + (lane << 2)] = o;
    }
  }
}

extern "C" void kernel_launch(void* const* d_in, const int* in_sizes, int n_in,
                              void* d_out, int out_size, void* d_ws, size_t ws_size,
                              hipStream_t stream) {
  const float* x   = (const float*)d_in[0];
  const int*   src = (const int*)d_in[1];
  const int*   dst = (const int*)d_in[2];
  const float* W1  = (const float*)d_in[3];
  const float* al1 = (const float*)d_in[4];
  const float* ar1 = (const float*)d_in[5];
  const float* W2  = (const float*)d_in[6];
  const float* al2 = (const float*)d_in[7];
  const float* ar2 = (const float*)d_in[8];
  float* out = (float*)d_out;

  // workspace layout
  float* ws = (float*)d_ws;
  float* el = ws;                           // NNODES*HH
  float* er = el + NNODES * HH;             // NNODES*HH
  int* deg     = (int*)(er + NNODES * HH);  // NNODES
  int* off     = deg + NNODES;              // NNODES+1
  int* cursor  = off + NNODES + 1;          // NNODES
  int* bsum    = cursor + NNODES;           // 256
  int* csr_src = bsum + 256;                // NEDGES
  uintptr_t p = ((uintptr_t)(csr_src + NEDGES) + 63) & ~(uintptr_t)63;
  _Float16* featb = (_Float16*)p;                  // NNODES*256 f16 (25.6 MB)
  _Float16* Apr = featb + (size_t)NNODES * 256;
  Apr = (_Float16*)(((uintptr_t)Apr + 63) & ~(uintptr_t)63);  // MPAD*512 f16
  _Float16* Bpr1 = Apr + (size_t)MPAD * 512;       // 256*512 f16
  _Float16* Bpr2 = Bpr1 + 256 * 512;               // 256*256 f16

  const int edgeBlocks = (NEDGES + 255) / 256;
  dim3 mfmaGrid(MPAD / 128, 2);

  // ---------- CSR build (shared by both layers) ----------
  hipMemsetAsync(deg, 0, NNODES * sizeof(int), stream);
  hist_kernel<<<edgeBlocks, 256, 0, stream>>>(dst, deg);
  scan_block_kernel<<<NB, 256, 0, stream>>>(deg, off, bsum);
  scan_top_kernel<<<1, 256, 0, stream>>>(bsum);
  scan_add_kernel<<<NB, 256, 0, stream>>>(off, bsum, cursor);
  scatter_kernel<<<edgeBlocks, 256, 0, stream>>>(src, dst, cursor, csr_src);

  // ---------- prep (fp16 A' + both B', one launch) ----------
  prep_kernel<<<MPAD / 2 + 768, 256, 0, stream>>>(x, W1, W2, Apr, Bpr1, Bpr2, NNODES);

  // ---------- layer 1 : K=512 ----------
  mfma_gemm_kernel<<<mfmaGrid, 256, 0, stream>>>(Apr, Bpr1, featb, al1, ar1, el, er, NNODES, 512);
  gat_agg_kernel<1><<<NNODES / 4, 256, 0, stream>>>(off, csr_src, el, er, featb, nullptr, Apr);

  // ---------- layer 2 : K=256 ----------
  mfma_gemm_kernel<<<mfmaGrid, 256, 0, stream>>>(Apr, Bpr2, featb, al2, ar2, el, er, NNODES, 256);
  gat_agg_kernel<2><<<NNODES / 4, 256, 0, stream>>>(off, csr_src, el, er, featb, out, nullptr);
}